// Round 11
// baseline (333.025 us; speedup 1.0000x reference)
//
#include <hip/hip_runtime.h>

typedef unsigned short u16;
typedef __attribute__((ext_vector_type(8))) short bf16x8v;
typedef __attribute__((ext_vector_type(4))) float f32x4v;

#define B_SZ 16384
#define F_SZ 50
#define E_SZ 64
#define D_SZ 512
#define H1_SZ 1024
#define H2_SZ 512
#define KL 3200   // lz K: k = f*64+e, f<50 -- NO padding (f-major)
#define KG 1280   // gram K: packed upper-tri 1275 -> padded 1280

__device__ __forceinline__ float b2f(u16 u){
  union { unsigned int i; float f; } v; v.i = ((unsigned int)u) << 16; return v.f;
}
__device__ __forceinline__ u16 f2b(float f){
  union { float f; unsigned int i; } v; v.f = f;
  unsigned int r = v.i + 0x7FFFu + ((v.i >> 16) & 1u);
  return (u16)(r >> 16);
}

// async global->LDS, 16B/lane. g is per-lane (base + lane*16B); lds base is
// wave-uniform; HW writes lds_base + lane*16.
__device__ __forceinline__ void gload16(const u16* g, u16* lds_base_uniform){
#if __has_builtin(__builtin_amdgcn_global_load_lds)
  __builtin_amdgcn_global_load_lds(
      (const __attribute__((address_space(1))) unsigned int*)g,
      (__attribute__((address_space(3))) unsigned int*)lds_base_uniform,
      16, 0, 0);
#else
  int lane = threadIdx.x & 63;
  *(uint4*)(lds_base_uniform + lane*8) = *(const uint4*)g;
#endif
}

// XCD-aware grid swizzle (r11: verified FETCH 270->99 MB): blocks sharing an
// A(m)-tile get IDs equal mod 8 -> same XCD L2. x = n-tile, y = m-tile.
__device__ __forceinline__ void swz(int id, int nblog2, int &x, int &y){
  int xcd = id & 7, j = id >> 3;
  x = j & ((1 << nblog2) - 1);
  y = ((j >> nblog2) << 3) | xcd;
}

// ---------------- front kernel v2 (r20): gather + Gram + weight prep.
// Gather section processes TWO b per block (waves 0-1 -> b0, 2-3 -> b1);
// embT written directly from registers. Ranges:
//   [0,8192)       gather/Gram for b = 2r, 2r+1
//   [8192,8704)    WlT  = bf16(product_linear)
//   [8704,9216)    pqq[d, packed(f,f')] = pq_f*pq_f'*(f==f'?1:2), pad 0
//   [9216,11264)   w0T (N,K) bf16
//   [11264,13312)  w1T (N,K) bf16
//   [13312,13344)  cvec = b0 + pbias @ w0
__global__ __launch_bounds__(256) void k_front(
    const int* __restrict__ fidx, const float* __restrict__ fval,
    const float* __restrict__ femb, u16* __restrict__ embT,
    u16* __restrict__ Gp,
    const float* __restrict__ Wl, u16* __restrict__ WlT,
    const float* __restrict__ Pq, u16* __restrict__ pqq,
    const float* __restrict__ w0, u16* __restrict__ w0T,
    const float* __restrict__ w1, u16* __restrict__ w1T,
    const float* __restrict__ pb, const float* __restrict__ b0,
    float* __restrict__ cvec)
{
  __shared__ int   sidx[2][F_SZ];
  __shared__ float sfv[2][F_SZ];
  __shared__ __align__(16) u16 tile[2][64*72];   // 18 KB (rows 50..63 garbage, masked)
  __shared__ __align__(16) u16 gbuf[2][KG];      // 5 KB
  const int r = blockIdx.x, t = threadIdx.x;
  if (r < 8192){
    const int h  = t >> 7;                 // which b this half-block serves
    const int th = t & 127;
    const int b  = r*2 + h;
    if (th < F_SZ){ sidx[h][th] = fidx[b*F_SZ+th]; sfv[h][th] = fval[b*F_SZ+th]; }
    if (th < 5) gbuf[h][1275+th] = 0;      // zero pad (NaN*0 hazard in MFMA)
    __syncthreads();
    u16* orow = embT + (size_t)b*KL;
    #pragma unroll
    for (int i=0;i<7;i++){
      int k4 = (i*128+th)*4;               // 4 consecutive e, same f
      if (k4 < F_SZ*E_SZ){
        int f = k4>>6, e = k4&63;
        float4 v = *(const float4*)&femb[(size_t)sidx[h][f]*E_SZ + e];
        float s = sfv[h][f];
        u16 q0=f2b(v.x*s), q1=f2b(v.y*s), q2=f2b(v.z*s), q3=f2b(v.w*s);
        tile[h][f*72+e+0]=q0; tile[h][f*72+e+1]=q1;
        tile[h][f*72+e+2]=q2; tile[h][f*72+e+3]=q3;
        union { unsigned long long d; u16 s4[4]; } o4;
        o4.s4[0]=q0; o4.s4[1]=q1; o4.s4[2]=q2; o4.s4[3]=q3;
        *(unsigned long long*)&orow[k4] = o4.d;   // direct 8 B embT store
      }
    }
    __syncthreads();
    // Gram -> gbuf packed upper-tri: idx(m,n) = 50m - m(m-1)/2 + (n-m), n>=m
    const int wave = t >> 6, lane = t & 63, quad = lane >> 4, l16 = lane & 15;
    const int hw = wave >> 1, lw = wave & 1;   // hw: which b, lw: wave-in-pair
    static const int TM[10] = {0,0,0,0,1,1,1,2,2,3};
    static const int TN[10] = {0,1,2,3,1,2,3,2,3,3};
    for (int ti = lw; ti < 10; ti += 2){
      const int tm = TM[ti], tn = TN[ti];
      f32x4v g = {0.f,0.f,0.f,0.f};
      #pragma unroll
      for (int ks=0;ks<2;ks++){
        bf16x8v af = *(const bf16x8v*)&tile[hw][(tm*16+l16)*72 + (ks*4+quad)*8];
        bf16x8v bf = *(const bf16x8v*)&tile[hw][(tn*16+l16)*72 + (ks*4+quad)*8];
        g = __builtin_amdgcn_mfma_f32_16x16x32_bf16(af, bf, g, 0, 0, 0);
      }
      const int gn = tn*16 + l16;          // C/D: n = lane&15, m = quad*4+r
      #pragma unroll
      for (int rr=0;rr<4;rr++){
        const int gm = tm*16 + quad*4 + rr;
        if (gm < F_SZ && gn < F_SZ && gn >= gm)
          gbuf[hw][gm*F_SZ - ((gm*(gm-1))>>1) + (gn-gm)] = f2b(g[rr]);
      }
    }
    __syncthreads();
    if (t < 160){
      #pragma unroll
      for (int hh=0; hh<2; hh++)
        *(uint4*)&Gp[(size_t)(r*2+hh)*KG + t*8] = *(const uint4*)&gbuf[hh][t*8];
    }
  } else if (r < 8704){
    const int d = r - 8192;
    #pragma unroll
    for (int i=0;i<4;i++){
      int k4 = (i*256+t)*4;
      if (k4 < KL){
        float4 v = *(const float4*)&Wl[(size_t)d*KL + k4];
        u16* o = &WlT[(size_t)d*KL + k4];
        o[0]=f2b(v.x); o[1]=f2b(v.y); o[2]=f2b(v.z); o[3]=f2b(v.w);
      }
    }
  } else if (r < 9216){
    const int d = r - 8704;
    const float* prow = &Pq[d*F_SZ];
    u16* orow = &pqq[(size_t)d*KG];
    int trif = 0;
    for (int f=0; f<F_SZ; f++){
      int len = F_SZ - f;
      if (t < len)
        orow[trif + t] = f2b(prow[f]*prow[f+t]*(t ? 2.f : 1.f));
      trif += len;
    }
    if (t < 5) orow[1275+t] = 0;
  } else if (r < 11264){
    int idx = (r-9216)*256 + t;          // 524288
    int k = idx & 511, n = idx >> 9;
    w0T[idx] = f2b(w0[(size_t)k*H1_SZ + n]);
  } else if (r < 13312){
    int idx = (r-11264)*256 + t;         // 524288
    int k = idx & 1023, n = idx >> 10;
    w1T[idx] = f2b(w1[(size_t)k*H2_SZ + n]);
  } else {
    int rr = r - 13312;
    int h = (rr & 3)*256 + t;
    int d0 = (rr >> 2)*64;
    float acc = (d0 == 0) ? b0[h] : 0.f;
    #pragma unroll 8
    for (int d=0; d<64; d++) acc += pb[d0+d]*w0[(size_t)(d0+d)*H1_SZ + h];
    atomicAdd(&cvec[h], acc);
  }
}

// BK=128 XOR-swizzled LDS tiles (r12 proven): rows are 256 B; LDS slot
// (row, block j in [0,16)) holds global block (j XOR (row&7)). Staged by
// lane fetching global block ((lane&15) XOR (row&7)) (4 rows/call);
// fragments read offset ((ks*4+quad) XOR (l16&7))*8.

// ---------------- fused product layer (r17 exact, measured 82.7 us):
// 128m x 128n tile, 64 KB LDS, 2 blocks/CU, 512-block grid, 32x128 wave
// tiles. r19's 64x64 variant regressed (108.9 us) -- do not change shape.
__global__ __launch_bounds__(256, 2) void k_prod(
    const u16* __restrict__ Ae,    // embT (B, KL)
    const u16* __restrict__ Bw,    // WlT  (D, KL)
    const u16* __restrict__ Ag,    // Gp   (B, KG)
    const u16* __restrict__ Bq,    // pqq  (D, KG)
    const float* __restrict__ pbias,
    u16* __restrict__ y0)          // (B, D)
{
  __shared__ __align__(16) u16 As[128*128];   // 32 KB
  __shared__ __align__(16) u16 Bs[128*128];   // 32 KB
  const int tid  = threadIdx.x;
  const int wave = tid >> 6, lane = tid & 63;
  const int quad = lane >> 4, l16 = lane & 15;
  int bx, by;  swz(blockIdx.x, 2, bx, by);    // 512 blocks: 4 n-tiles, 128 m-tiles
  const int n0 = bx * 128, m0 = by * 128;
  const int lr4 = lane >> 4;
  const int cb  = lane & 15;
  const int sw  = (l16 & 7);

  f32x4v acc1[2][8], acc2[2][8];
  #pragma unroll
  for (int i=0;i<2;i++)
    #pragma unroll
    for (int j=0;j<8;j++){
      acc1[i][j] = (f32x4v){0.f,0.f,0.f,0.f};
      acc2[i][j] = (f32x4v){0.f,0.f,0.f,0.f};
    }

  auto run = [&](const u16* Ap, const u16* Bp, int K, f32x4v (&acc)[2][8]){
    for (int k0 = 0; k0 < K; k0 += 128){
      __syncthreads();
      #pragma unroll
      for (int c=0;c<8;c++){
        const int r0 = wave*32 + c*4;
        const int row = r0 + lr4;
        gload16(Ap + (size_t)(m0 + row)*K + k0 + ((cb ^ (row & 7)) << 3), As + r0*128);
      }
      #pragma unroll
      for (int c=0;c<8;c++){
        const int r0 = wave*32 + c*4;
        const int row = r0 + lr4;
        gload16(Bp + (size_t)(n0 + row)*K + k0 + ((cb ^ (row & 7)) << 3), Bs + r0*128);
      }
      __syncthreads();
      #pragma unroll
      for (int ks=0; ks<4; ks++){
        bf16x8v af[2], bfr[8];
        #pragma unroll
        for (int mt=0;mt<2;mt++)
          af[mt] = *(const bf16x8v*)&As[(wave*32+mt*16+l16)*128 + (((ks*4+quad) ^ sw))*8];
        #pragma unroll
        for (int nt=0;nt<8;nt++)
          bfr[nt] = *(const bf16x8v*)&Bs[(nt*16+l16)*128 + (((ks*4+quad) ^ sw))*8];
        #pragma unroll
        for (int mt=0;mt<2;mt++)
          #pragma unroll
          for (int nt=0;nt<8;nt++)
            acc[mt][nt] = __builtin_amdgcn_mfma_f32_16x16x32_bf16(af[mt], bfr[nt], acc[mt][nt], 0, 0, 0);
      }
    }
  };

  run(Ae, Bw, KL, acc1);     // lz
  run(Ag, Bq, KG, acc2);     // lp^2

  #pragma unroll
  for (int nt=0;nt<8;nt++){
    const int n = n0 + nt*16 + l16;
    const float bv = pbias[n];
    #pragma unroll
    for (int mt=0;mt<2;mt++){
      const int mb = m0 + wave*32 + mt*16 + quad*4;
      #pragma unroll
      for (int r=0;r<4;r++){
        float v = acc1[mt][nt][r] + sqrtf(fmaxf(acc2[mt][nt][r], 0.f)) + bv;
        v = (v > 0.f ? v : 0.f) - bv;
        y0[(size_t)(mb+r)*D_SZ + n] = f2b(v);
      }
    }
  }
}

// ---------------- BT GEMM v4 (r21): 128m x 128n tile, BK=128, 64 KB LDS,
// 2 blocks/CU -- the k_prod-proven body with one accumulator set + stats
// epilogue. vs the 64m version: B-staging through L2 halves (K*N*(M/128)),
// gemm0 = 1024 blocks = exactly 2 residency rounds (was 2.67), gemm1 = 512
// = 1 round. Stats: store centered acc (bf16), stats over acc+bias[n];
// atomic count per column unchanged (512).
__global__ __launch_bounds__(256, 2) void gemm_bt(
    const u16* __restrict__ A, const u16* __restrict__ Bm,
    u16* __restrict__ C, const float* __restrict__ bias,
    float* __restrict__ S1, float* __restrict__ S2,
    int nblog2, int N, int K)
{
  __shared__ __align__(16) u16 As[128*128];   // 32 KB
  __shared__ __align__(16) u16 Bs[128*128];   // 32 KB
  const int tid  = threadIdx.x;
  const int wave = tid >> 6, lane = tid & 63;
  const int quad = lane >> 4, l16 = lane & 15;
  int bx, by;  swz(blockIdx.x, nblog2, bx, by);
  const int n0 = bx * 128, m0 = by * 128;
  const int lr4 = lane >> 4;
  const int cb  = lane & 15;
  const int sw  = (l16 & 7);

  f32x4v acc[2][8];
  #pragma unroll
  for (int i=0;i<2;i++)
    #pragma unroll
    for (int j=0;j<8;j++)
      acc[i][j] = (f32x4v){0.f,0.f,0.f,0.f};

  for (int k0 = 0; k0 < K; k0 += 128){
    __syncthreads();
    #pragma unroll
    for (int c=0;c<8;c++){
      const int r0 = wave*32 + c*4;
      const int row = r0 + lr4;
      gload16(A + (size_t)(m0 + row)*K + k0 + ((cb ^ (row & 7)) << 3), As + r0*128);
    }
    #pragma unroll
    for (int c=0;c<8;c++){
      const int r0 = wave*32 + c*4;
      const int row = r0 + lr4;
      gload16(Bm + (size_t)(n0 + row)*K + k0 + ((cb ^ (row & 7)) << 3), Bs + r0*128);
    }
    __syncthreads();
    #pragma unroll
    for (int ks=0; ks<4; ks++){
      bf16x8v af[2], bfr[8];
      #pragma unroll
      for (int mt=0;mt<2;mt++)
        af[mt] = *(const bf16x8v*)&As[(wave*32+mt*16+l16)*128 + (((ks*4+quad) ^ sw))*8];
      #pragma unroll
      for (int nt=0;nt<8;nt++)
        bfr[nt] = *(const bf16x8v*)&Bs[(nt*16+l16)*128 + (((ks*4+quad) ^ sw))*8];
      #pragma unroll
      for (int mt=0;mt<2;mt++)
        #pragma unroll
        for (int nt=0;nt<8;nt++)
          acc[mt][nt] = __builtin_amdgcn_mfma_f32_16x16x32_bf16(af[mt], bfr[nt], acc[mt][nt], 0, 0, 0);
    }
  }

  // epilogue; C/D layout: n = lane&15, m = quad*4 + reg
  #pragma unroll
  for (int nt=0;nt<8;nt++){
    const int n = n0 + nt*16 + l16;
    const float bv = bias[n];
    float ls1 = 0.f, ls2 = 0.f;
    #pragma unroll
    for (int mt=0;mt<2;mt++){
      const int mb = m0 + wave*32 + mt*16 + quad*4;
      #pragma unroll
      for (int r=0;r<4;r++){
        float v = acc[mt][nt][r] + bv;
        C[(size_t)(mb+r)*N + n] = f2b(acc[mt][nt][r]);   // centered store
        ls1 += v; ls2 += v*v;
      }
    }
    ls1 += __shfl_xor(ls1, 16); ls2 += __shfl_xor(ls2, 16);
    ls1 += __shfl_xor(ls1, 32); ls2 += __shfl_xor(ls2, 32);
    if (quad == 0){ atomicAdd(&S1[n], ls1); atomicAdd(&S2[n], ls2); }
  }
}

// ---------------- BN apply + relu with inlined stats finalize (r17):
// bf16 centered Z in, bf16 Y out, 8/thread. Stored z is (z_full - cadd):
// b = bnof - m*a + a*cadd[n].
__global__ __launch_bounds__(256) void k_bnapply(
    const u16* __restrict__ Z, u16* __restrict__ Y,
    const float* __restrict__ S1, const float* __restrict__ S2,
    const float* __restrict__ bnsc, const float* __restrict__ bnof,
    const float* __restrict__ cadd, int nmask)
{
  size_t base = ((size_t)blockIdx.x*256 + threadIdx.x) * 8;
  int n0 = (int)(base & (size_t)nmask);
  const float invB = 1.f / 16384.f;
  const float sc = bnsc[0], of = bnof[0];
  union { uint4 q; u16 s[8]; } z, o;
  z.q = *(const uint4*)&Z[base];
  #pragma unroll
  for (int j=0;j<8;j++){
    int n = n0 + j;
    float m   = S1[n]*invB;
    float var = S2[n]*invB - m*m;
    float a   = sc * rsqrtf(var + 1e-10f);
    float bb  = of - m*a + a*cadd[n];
    float v = b2f(z.s[j]) * a + bb;
    o.s[j] = f2b(v > 0.f ? v : 0.f);
  }
  *(uint4*)&Y[base] = o.q;
}

// ---------------- final: inlined BN finalize + relu + dot + sigmoid (r17).
__global__ __launch_bounds__(256) void k_out(
    const u16* __restrict__ Z2, const float* __restrict__ wvec,
    const float* __restrict__ obp,
    const float* __restrict__ S1, const float* __restrict__ S2,
    const float* __restrict__ bnsc, const float* __restrict__ bnof,
    const float* __restrict__ cadd,
    float* __restrict__ out)
{
  const int wave = threadIdx.x >> 6, lane = threadIdx.x & 63;
  const int b = blockIdx.x*4 + wave;
  const int n0 = lane*8;
  const float invB = 1.f / 16384.f;
  const float sc = bnsc[0], of = bnof[0];
  union { uint4 q; u16 s[8]; } z;
  z.q = *(const uint4*)&Z2[(size_t)b*H2_SZ + n0];
  float4 wa = *(const float4*)&wvec[n0];
  float4 wb = *(const float4*)&wvec[n0+4];
  float wv[8] = {wa.x,wa.y,wa.z,wa.w,wb.x,wb.y,wb.z,wb.w};
  float s = 0.f;
  #pragma unroll
  for (int j=0;j<8;j++){
    int n = n0 + j;
    float m   = S1[n]*invB;
    float var = S2[n]*invB - m*m;
    float a   = sc * rsqrtf(var + 1e-10f);
    float bb  = of - m*a + a*cadd[n];
    float y = b2f(z.s[j]) * a + bb;
    y = y > 0.f ? y : 0.f;
    s += y * wv[j];
  }
  s += __shfl_xor(s,1);  s += __shfl_xor(s,2);  s += __shfl_xor(s,4);
  s += __shfl_xor(s,8);  s += __shfl_xor(s,16); s += __shfl_xor(s,32);
  if (lane == 0){
    float x = s + obp[0];
    out[b] = 1.f / (1.f + expf(-x));
  }
}

// ---------------- workspace map (bytes) ----------------
// embT @ 0          : 104857600  (B x 3200 bf16; dead after k_prod; reused:)
//   z1c @ 0         :  33554432  (bf16 centered pre-BN layer0)
//   y1  @ 67108864  :  33554432  (bf16 post-BN layer0)
//   z2c @ 100663296 :  16777216  (bf16 centered pre-BN layer1)
// Gp   @ 104857600  :  41943040  (B x 1280 bf16; dead after k_prod)
// WlT  @ 146800640  :   3276800
// pqq  @ 150077440  :   1310720
// y0   @ 151388160  :  16777216  (bf16, bias-centered)
// W0T  @ 168165376  :   1048576
// W1T  @ 169213952  :   1048576
// stats@ 170262528  : 16 KB ZEROED: S1a[1024] S2a[1024] S1b[512] S2b[512] cvec[1024]
// total ~ 170.3 MB

extern "C" void kernel_launch(void* const* d_in, const int* in_sizes, int n_in,
                              void* d_out, int out_size, void* d_ws, size_t ws_size,
                              hipStream_t stream)
{
  const int*   fidx  = (const int*)d_in[0];
  const float* fval  = (const float*)d_in[1];
  const float* femb  = (const float*)d_in[2];
  const float* wl    = (const float*)d_in[3];
  const float* pbias = (const float*)d_in[4];
  const float* pq    = (const float*)d_in[5];
  const float* w0    = (const float*)d_in[6];
  const float* b0    = (const float*)d_in[7];
  const float* w1    = (const float*)d_in[8];
  const float* b1    = (const float*)d_in[9];
  const float* bnsc  = (const float*)d_in[10];
  const float* bnof  = (const float*)d_in[11];
  const float* ow    = (const float*)d_in[12];
  const float* ob    = (const float*)d_in[13];
  float* out = (float*)d_out;

  char* ws = (char*)d_ws;
  u16*   embT = (u16*)(ws + 0);
  u16*   z1b  = (u16*)(ws + 0);
  u16*   y1b  = (u16*)(ws + 67108864);
  u16*   z2b  = (u16*)(ws + 100663296);
  u16*   gpb  = (u16*)(ws + 104857600);
  u16*   wlT  = (u16*)(ws + 146800640);
  u16*   pqqb = (u16*)(ws + 150077440);
  u16*   y0b  = (u16*)(ws + 151388160);
  u16*   w0T  = (u16*)(ws + 168165376);
  u16*   w1T  = (u16*)(ws + 169213952);
  float* S1a  = (float*)(ws + 170262528);
  float* S2a  = S1a + 1024;
  float* S1b  = S2a + 1024;
  float* S2b  = S1b + 512;
  float* cvec = S2b + 512;

  hipMemsetAsync((void*)S1a, 0, 16384, stream);      // S1a,S2a,S1b,S2b,cvec

  k_front<<<13344, 256, 0, stream>>>(fidx, fval, femb, embT, gpb,
                                     wl, wlT, pq, pqqb, w0, w0T, w1, w1T,
                                     pbias, b0, cvec);

  k_prod<<<512, 256, 0, stream>>>(embT, wlT, gpb, pqqb, pbias, y0b);

  // layer 0: z1c (centered bf16) + batch stats; 1024 blocks (8 n-tiles)
  gemm_bt<<<1024, 256, 0, stream>>>(y0b, w0T, z1b, cvec, S1a, S2a,
                                    3, H1_SZ, D_SZ);
  k_bnapply<<<8192, 256, 0, stream>>>(z1b, y1b, S1a, S2a, bnsc, bnof, cvec, 1023);

  // layer 1: z2c (centered bf16) + batch stats; 512 blocks (4 n-tiles)
  gemm_bt<<<512, 256, 0, stream>>>(y1b, w1T, z2b, b1, S1b, S2b,
                                   2, H2_SZ, H1_SZ);

  k_out<<<4096, 256, 0, stream>>>(z2b, ow, ob, S1b, S2b, bnsc, bnof, b1, out);
}

// Round 12
// 329.326 us; speedup vs baseline: 1.0112x; 1.0112x over previous
//
#include <hip/hip_runtime.h>

typedef unsigned short u16;
typedef __attribute__((ext_vector_type(8))) short bf16x8v;
typedef __attribute__((ext_vector_type(4))) float f32x4v;

#define B_SZ 16384
#define F_SZ 50
#define E_SZ 64
#define D_SZ 512
#define H1_SZ 1024
#define H2_SZ 512
#define KL 3200   // lz K: k = f*64+e, f<50 -- NO padding (f-major)
#define KG 1280   // gram K: packed upper-tri 1275 -> padded 1280

__device__ __forceinline__ float b2f(u16 u){
  union { unsigned int i; float f; } v; v.i = ((unsigned int)u) << 16; return v.f;
}
__device__ __forceinline__ u16 f2b(float f){
  union { float f; unsigned int i; } v; v.f = f;
  unsigned int r = v.i + 0x7FFFu + ((v.i >> 16) & 1u);
  return (u16)(r >> 16);
}

// async global->LDS, 16B/lane. g is per-lane (base + lane*16B); lds base is
// wave-uniform; HW writes lds_base + lane*16.
__device__ __forceinline__ void gload16(const u16* g, u16* lds_base_uniform){
#if __has_builtin(__builtin_amdgcn_global_load_lds)
  __builtin_amdgcn_global_load_lds(
      (const __attribute__((address_space(1))) unsigned int*)g,
      (__attribute__((address_space(3))) unsigned int*)lds_base_uniform,
      16, 0, 0);
#else
  int lane = threadIdx.x & 63;
  *(uint4*)(lds_base_uniform + lane*8) = *(const uint4*)g;
#endif
}

// XCD-aware grid swizzle (r11: verified FETCH 270->99 MB): blocks sharing an
// A(m)-tile get IDs equal mod 8 -> same XCD L2. x = n-tile, y = m-tile.
__device__ __forceinline__ void swz(int id, int nblog2, int &x, int &y){
  int xcd = id & 7, j = id >> 3;
  x = j & ((1 << nblog2) - 1);
  y = ((j >> nblog2) << 3) | xcd;
}

// ---------------- front kernel v2 (r20, measured best): gather + Gram +
// weight prep. Gather: TWO b per block (halved launch count), embT written
// directly from registers. Ranges:
//   [0,8192)       gather/Gram for b = 2r, 2r+1
//   [8192,8704)    WlT  = bf16(product_linear)
//   [8704,9216)    pqq[d, packed(f,f')] = pq_f*pq_f'*(f==f'?1:2), pad 0
//   [9216,11264)   w0T (N,K) bf16
//   [11264,13312)  w1T (N,K) bf16
//   [13312,13344)  cvec = b0 + pbias @ w0
__global__ __launch_bounds__(256) void k_front(
    const int* __restrict__ fidx, const float* __restrict__ fval,
    const float* __restrict__ femb, u16* __restrict__ embT,
    u16* __restrict__ Gp,
    const float* __restrict__ Wl, u16* __restrict__ WlT,
    const float* __restrict__ Pq, u16* __restrict__ pqq,
    const float* __restrict__ w0, u16* __restrict__ w0T,
    const float* __restrict__ w1, u16* __restrict__ w1T,
    const float* __restrict__ pb, const float* __restrict__ b0,
    float* __restrict__ cvec)
{
  __shared__ int   sidx[2][F_SZ];
  __shared__ float sfv[2][F_SZ];
  __shared__ __align__(16) u16 tile[2][64*72];   // 18 KB (rows 50..63 garbage, masked)
  __shared__ __align__(16) u16 gbuf[2][KG];      // 5 KB
  const int r = blockIdx.x, t = threadIdx.x;
  if (r < 8192){
    const int h  = t >> 7;                 // which b this half-block serves
    const int th = t & 127;
    const int b  = r*2 + h;
    if (th < F_SZ){ sidx[h][th] = fidx[b*F_SZ+th]; sfv[h][th] = fval[b*F_SZ+th]; }
    if (th < 5) gbuf[h][1275+th] = 0;      // zero pad (NaN*0 hazard in MFMA)
    __syncthreads();
    u16* orow = embT + (size_t)b*KL;
    #pragma unroll
    for (int i=0;i<7;i++){
      int k4 = (i*128+th)*4;               // 4 consecutive e, same f
      if (k4 < F_SZ*E_SZ){
        int f = k4>>6, e = k4&63;
        float4 v = *(const float4*)&femb[(size_t)sidx[h][f]*E_SZ + e];
        float s = sfv[h][f];
        u16 q0=f2b(v.x*s), q1=f2b(v.y*s), q2=f2b(v.z*s), q3=f2b(v.w*s);
        tile[h][f*72+e+0]=q0; tile[h][f*72+e+1]=q1;
        tile[h][f*72+e+2]=q2; tile[h][f*72+e+3]=q3;
        union { unsigned long long d; u16 s4[4]; } o4;
        o4.s4[0]=q0; o4.s4[1]=q1; o4.s4[2]=q2; o4.s4[3]=q3;
        *(unsigned long long*)&orow[k4] = o4.d;   // direct 8 B embT store
      }
    }
    __syncthreads();
    // Gram -> gbuf packed upper-tri: idx(m,n) = 50m - m(m-1)/2 + (n-m), n>=m
    const int wave = t >> 6, lane = t & 63, quad = lane >> 4, l16 = lane & 15;
    const int hw = wave >> 1, lw = wave & 1;   // hw: which b, lw: wave-in-pair
    static const int TM[10] = {0,0,0,0,1,1,1,2,2,3};
    static const int TN[10] = {0,1,2,3,1,2,3,2,3,3};
    for (int ti = lw; ti < 10; ti += 2){
      const int tm = TM[ti], tn = TN[ti];
      f32x4v g = {0.f,0.f,0.f,0.f};
      #pragma unroll
      for (int ks=0;ks<2;ks++){
        bf16x8v af = *(const bf16x8v*)&tile[hw][(tm*16+l16)*72 + (ks*4+quad)*8];
        bf16x8v bf = *(const bf16x8v*)&tile[hw][(tn*16+l16)*72 + (ks*4+quad)*8];
        g = __builtin_amdgcn_mfma_f32_16x16x32_bf16(af, bf, g, 0, 0, 0);
      }
      const int gn = tn*16 + l16;          // C/D: n = lane&15, m = quad*4+r
      #pragma unroll
      for (int rr=0;rr<4;rr++){
        const int gm = tm*16 + quad*4 + rr;
        if (gm < F_SZ && gn < F_SZ && gn >= gm)
          gbuf[hw][gm*F_SZ - ((gm*(gm-1))>>1) + (gn-gm)] = f2b(g[rr]);
      }
    }
    __syncthreads();
    if (t < 160){
      #pragma unroll
      for (int hh=0; hh<2; hh++)
        *(uint4*)&Gp[(size_t)(r*2+hh)*KG + t*8] = *(const uint4*)&gbuf[hh][t*8];
    }
  } else if (r < 8704){
    const int d = r - 8192;
    #pragma unroll
    for (int i=0;i<4;i++){
      int k4 = (i*256+t)*4;
      if (k4 < KL){
        float4 v = *(const float4*)&Wl[(size_t)d*KL + k4];
        u16* o = &WlT[(size_t)d*KL + k4];
        o[0]=f2b(v.x); o[1]=f2b(v.y); o[2]=f2b(v.z); o[3]=f2b(v.w);
      }
    }
  } else if (r < 9216){
    const int d = r - 8704;
    const float* prow = &Pq[d*F_SZ];
    u16* orow = &pqq[(size_t)d*KG];
    int trif = 0;
    for (int f=0; f<F_SZ; f++){
      int len = F_SZ - f;
      if (t < len)
        orow[trif + t] = f2b(prow[f]*prow[f+t]*(t ? 2.f : 1.f));
      trif += len;
    }
    if (t < 5) orow[1275+t] = 0;
  } else if (r < 11264){
    int idx = (r-9216)*256 + t;          // 524288
    int k = idx & 511, n = idx >> 9;
    w0T[idx] = f2b(w0[(size_t)k*H1_SZ + n]);
  } else if (r < 13312){
    int idx = (r-11264)*256 + t;         // 524288
    int k = idx & 1023, n = idx >> 10;
    w1T[idx] = f2b(w1[(size_t)k*H2_SZ + n]);
  } else {
    int rr = r - 13312;
    int h = (rr & 3)*256 + t;
    int d0 = (rr >> 2)*64;
    float acc = (d0 == 0) ? b0[h] : 0.f;
    #pragma unroll 8
    for (int d=0; d<64; d++) acc += pb[d0+d]*w0[(size_t)(d0+d)*H1_SZ + h];
    atomicAdd(&cvec[h], acc);
  }
}

// BK=128 XOR-swizzled LDS tiles (r12 proven): rows are 256 B; LDS slot
// (row, block j in [0,16)) holds global block (j XOR (row&7)). Staged by
// lane fetching global block ((lane&15) XOR (row&7)) (4 rows/call);
// fragments read offset ((ks*4+quad) XOR (l16&7))*8.

// ---------------- fused product layer (r17 exact, measured 82.7 us):
// 128m x 128n tile, 64 KB LDS, 2 blocks/CU, 512-block grid, 32x128 wave
// tiles. FROZEN: r19's 64x64 tiles (108.9) and r21-style resizing both
// regressed -- do not change shape.
__global__ __launch_bounds__(256, 2) void k_prod(
    const u16* __restrict__ Ae,    // embT (B, KL)
    const u16* __restrict__ Bw,    // WlT  (D, KL)
    const u16* __restrict__ Ag,    // Gp   (B, KG)
    const u16* __restrict__ Bq,    // pqq  (D, KG)
    const float* __restrict__ pbias,
    u16* __restrict__ y0)          // (B, D)
{
  __shared__ __align__(16) u16 As[128*128];   // 32 KB
  __shared__ __align__(16) u16 Bs[128*128];   // 32 KB
  const int tid  = threadIdx.x;
  const int wave = tid >> 6, lane = tid & 63;
  const int quad = lane >> 4, l16 = lane & 15;
  int bx, by;  swz(blockIdx.x, 2, bx, by);    // 512 blocks: 4 n-tiles, 128 m-tiles
  const int n0 = bx * 128, m0 = by * 128;
  const int lr4 = lane >> 4;
  const int cb  = lane & 15;
  const int sw  = (l16 & 7);

  f32x4v acc1[2][8], acc2[2][8];
  #pragma unroll
  for (int i=0;i<2;i++)
    #pragma unroll
    for (int j=0;j<8;j++){
      acc1[i][j] = (f32x4v){0.f,0.f,0.f,0.f};
      acc2[i][j] = (f32x4v){0.f,0.f,0.f,0.f};
    }

  auto run = [&](const u16* Ap, const u16* Bp, int K, f32x4v (&acc)[2][8]){
    for (int k0 = 0; k0 < K; k0 += 128){
      __syncthreads();
      #pragma unroll
      for (int c=0;c<8;c++){
        const int r0 = wave*32 + c*4;
        const int row = r0 + lr4;
        gload16(Ap + (size_t)(m0 + row)*K + k0 + ((cb ^ (row & 7)) << 3), As + r0*128);
      }
      #pragma unroll
      for (int c=0;c<8;c++){
        const int r0 = wave*32 + c*4;
        const int row = r0 + lr4;
        gload16(Bp + (size_t)(n0 + row)*K + k0 + ((cb ^ (row & 7)) << 3), Bs + r0*128);
      }
      __syncthreads();
      #pragma unroll
      for (int ks=0; ks<4; ks++){
        bf16x8v af[2], bfr[8];
        #pragma unroll
        for (int mt=0;mt<2;mt++)
          af[mt] = *(const bf16x8v*)&As[(wave*32+mt*16+l16)*128 + (((ks*4+quad) ^ sw))*8];
        #pragma unroll
        for (int nt=0;nt<8;nt++)
          bfr[nt] = *(const bf16x8v*)&Bs[(nt*16+l16)*128 + (((ks*4+quad) ^ sw))*8];
        #pragma unroll
        for (int mt=0;mt<2;mt++)
          #pragma unroll
          for (int nt=0;nt<8;nt++)
            acc[mt][nt] = __builtin_amdgcn_mfma_f32_16x16x32_bf16(af[mt], bfr[nt], acc[mt][nt], 0, 0, 0);
      }
    }
  };

  run(Ae, Bw, KL, acc1);     // lz
  run(Ag, Bq, KG, acc2);     // lp^2

  #pragma unroll
  for (int nt=0;nt<8;nt++){
    const int n = n0 + nt*16 + l16;
    const float bv = pbias[n];
    #pragma unroll
    for (int mt=0;mt<2;mt++){
      const int mb = m0 + wave*32 + mt*16 + quad*4;
      #pragma unroll
      for (int r=0;r<4;r++){
        float v = acc1[mt][nt][r] + sqrtf(fmaxf(acc2[mt][nt][r], 0.f)) + bv;
        v = (v > 0.f ? v : 0.f) - bv;
        y0[(size_t)(mb+r)*D_SZ + n] = f2b(v);
      }
    }
  }
}

// ---------------- BT GEMM v3 (r12 exact, FROZEN): BK=128, 64m x 128n,
// 256 threads, 48 KB LDS (3 blocks/CU). r21's 128m variant regressed
// (+9.4 us) -- B-staging is L2-resident and was never the constraint.
// Stats over v = acc+bias[n]; store centered acc (pre-bias) as bf16.
__global__ __launch_bounds__(256) void gemm_bt(
    const u16* __restrict__ A, const u16* __restrict__ Bm,
    u16* __restrict__ C, const float* __restrict__ bias,
    float* __restrict__ S1, float* __restrict__ S2,
    int nblog2, int N, int K)
{
  __shared__ __align__(16) u16 As[64*128];    // 16 KB
  __shared__ __align__(16) u16 Bs[128*128];   // 32 KB
  const int tid  = threadIdx.x;
  const int wave = tid >> 6, lane = tid & 63;
  const int quad = lane >> 4, l16 = lane & 15;
  int bx, by;  swz(blockIdx.x, nblog2, bx, by);
  const int n0 = bx * 128, m0 = by * 64;
  const int wr = wave >> 1, wc = wave & 1;
  const int lr4 = lane >> 4;
  const int cb  = lane & 15;
  const int sw  = (l16 & 7);

  f32x4v acc[2][4];
  #pragma unroll
  for (int i=0;i<2;i++)
    #pragma unroll
    for (int j=0;j<4;j++)
      acc[i][j] = (f32x4v){0.f,0.f,0.f,0.f};

  for (int k0 = 0; k0 < K; k0 += 128){
    __syncthreads();
    #pragma unroll
    for (int c=0;c<4;c++){
      const int r0 = wave*16 + c*4;
      const int row = r0 + lr4;
      gload16(A + (size_t)(m0 + row)*K + k0 + ((cb ^ (row & 7)) << 3), As + r0*128);
    }
    #pragma unroll
    for (int c=0;c<8;c++){
      const int r0 = wave*32 + c*4;
      const int row = r0 + lr4;
      gload16(Bm + (size_t)(n0 + row)*K + k0 + ((cb ^ (row & 7)) << 3), Bs + r0*128);
    }
    __syncthreads();
    #pragma unroll
    for (int ks=0; ks<4; ks++){
      bf16x8v af[2], bfr[4];
      #pragma unroll
      for (int mt=0;mt<2;mt++)
        af[mt] = *(const bf16x8v*)&As[(wr*32+mt*16+l16)*128 + (((ks*4+quad) ^ sw))*8];
      #pragma unroll
      for (int nt=0;nt<4;nt++)
        bfr[nt] = *(const bf16x8v*)&Bs[(wc*64+nt*16+l16)*128 + (((ks*4+quad) ^ sw))*8];
      #pragma unroll
      for (int mt=0;mt<2;mt++)
        #pragma unroll
        for (int nt=0;nt<4;nt++)
          acc[mt][nt] = __builtin_amdgcn_mfma_f32_16x16x32_bf16(af[mt], bfr[nt], acc[mt][nt], 0, 0, 0);
    }
  }

  // epilogue; C/D layout: n = lane&15, m = quad*4 + reg
  #pragma unroll
  for (int nt=0;nt<4;nt++){
    const int n = n0 + wc*64 + nt*16 + l16;
    const float bv = bias[n];
    float ls1 = 0.f, ls2 = 0.f;
    #pragma unroll
    for (int mt=0;mt<2;mt++){
      const int mb = m0 + wr*32 + mt*16 + quad*4;
      #pragma unroll
      for (int r=0;r<4;r++){
        float v = acc[mt][nt][r] + bv;
        C[(size_t)(mb+r)*N + n] = f2b(acc[mt][nt][r]);   // centered store
        ls1 += v; ls2 += v*v;
      }
    }
    ls1 += __shfl_xor(ls1, 16); ls2 += __shfl_xor(ls2, 16);
    ls1 += __shfl_xor(ls1, 32); ls2 += __shfl_xor(ls2, 32);
    if (quad == 0){ atomicAdd(&S1[n], ls1); atomicAdd(&S2[n], ls2); }
  }
}

// ---------------- BN apply + relu with inlined stats finalize (r22):
// 16 elems/thread (4096 blocks -- halved launch/addr overhead vs r17's 8).
// Stored z is (z_full - cadd): b = bnof - m*a + a*cadd[n].
__global__ __launch_bounds__(256) void k_bnapply(
    const u16* __restrict__ Z, u16* __restrict__ Y,
    const float* __restrict__ S1, const float* __restrict__ S2,
    const float* __restrict__ bnsc, const float* __restrict__ bnof,
    const float* __restrict__ cadd, int nmask)
{
  size_t base = ((size_t)blockIdx.x*256 + threadIdx.x) * 16;
  int n0 = (int)(base & (size_t)nmask);
  const float invB = 1.f / 16384.f;
  const float sc = bnsc[0], of = bnof[0];
  #pragma unroll
  for (int half=0; half<2; half++){
    union { uint4 q; u16 s[8]; } z, o;
    z.q = *(const uint4*)&Z[base + half*8];
    #pragma unroll
    for (int j=0;j<8;j++){
      int n = n0 + half*8 + j;
      float m   = S1[n]*invB;
      float var = S2[n]*invB - m*m;
      float a   = sc * rsqrtf(var + 1e-10f);
      float bb  = of - m*a + a*cadd[n];
      float v = b2f(z.s[j]) * a + bb;
      o.s[j] = f2b(v > 0.f ? v : 0.f);
    }
    *(uint4*)&Y[base + half*8] = o.q;
  }
}

// ---------------- final: inlined BN finalize + relu + dot + sigmoid (r17).
__global__ __launch_bounds__(256) void k_out(
    const u16* __restrict__ Z2, const float* __restrict__ wvec,
    const float* __restrict__ obp,
    const float* __restrict__ S1, const float* __restrict__ S2,
    const float* __restrict__ bnsc, const float* __restrict__ bnof,
    const float* __restrict__ cadd,
    float* __restrict__ out)
{
  const int wave = threadIdx.x >> 6, lane = threadIdx.x & 63;
  const int b = blockIdx.x*4 + wave;
  const int n0 = lane*8;
  const float invB = 1.f / 16384.f;
  const float sc = bnsc[0], of = bnof[0];
  union { uint4 q; u16 s[8]; } z;
  z.q = *(const uint4*)&Z2[(size_t)b*H2_SZ + n0];
  float4 wa = *(const float4*)&wvec[n0];
  float4 wb = *(const float4*)&wvec[n0+4];
  float wv[8] = {wa.x,wa.y,wa.z,wa.w,wb.x,wb.y,wb.z,wb.w};
  float s = 0.f;
  #pragma unroll
  for (int j=0;j<8;j++){
    int n = n0 + j;
    float m   = S1[n]*invB;
    float var = S2[n]*invB - m*m;
    float a   = sc * rsqrtf(var + 1e-10f);
    float bb  = of - m*a + a*cadd[n];
    float y = b2f(z.s[j]) * a + bb;
    y = y > 0.f ? y : 0.f;
    s += y * wv[j];
  }
  s += __shfl_xor(s,1);  s += __shfl_xor(s,2);  s += __shfl_xor(s,4);
  s += __shfl_xor(s,8);  s += __shfl_xor(s,16); s += __shfl_xor(s,32);
  if (lane == 0){
    float x = s + obp[0];
    out[b] = 1.f / (1.f + expf(-x));
  }
}

// ---------------- workspace map (bytes) ----------------
// embT @ 0          : 104857600  (B x 3200 bf16; dead after k_prod; reused:)
//   z1c @ 0         :  33554432  (bf16 centered pre-BN layer0)
//   y1  @ 67108864  :  33554432  (bf16 post-BN layer0)
//   z2c @ 100663296 :  16777216  (bf16 centered pre-BN layer1)
// Gp   @ 104857600  :  41943040  (B x 1280 bf16; dead after k_prod)
// WlT  @ 146800640  :   3276800
// pqq  @ 150077440  :   1310720
// y0   @ 151388160  :  16777216  (bf16, bias-centered)
// W0T  @ 168165376  :   1048576
// W1T  @ 169213952  :   1048576
// stats@ 170262528  : 16 KB ZEROED: S1a[1024] S2a[1024] S1b[512] S2b[512] cvec[1024]
// total ~ 170.3 MB

extern "C" void kernel_launch(void* const* d_in, const int* in_sizes, int n_in,
                              void* d_out, int out_size, void* d_ws, size_t ws_size,
                              hipStream_t stream)
{
  const int*   fidx  = (const int*)d_in[0];
  const float* fval  = (const float*)d_in[1];
  const float* femb  = (const float*)d_in[2];
  const float* wl    = (const float*)d_in[3];
  const float* pbias = (const float*)d_in[4];
  const float* pq    = (const float*)d_in[5];
  const float* w0    = (const float*)d_in[6];
  const float* b0    = (const float*)d_in[7];
  const float* w1    = (const float*)d_in[8];
  const float* b1    = (const float*)d_in[9];
  const float* bnsc  = (const float*)d_in[10];
  const float* bnof  = (const float*)d_in[11];
  const float* ow    = (const float*)d_in[12];
  const float* ob    = (const float*)d_in[13];
  float* out = (float*)d_out;

  char* ws = (char*)d_ws;
  u16*   embT = (u16*)(ws + 0);
  u16*   z1b  = (u16*)(ws + 0);
  u16*   y1b  = (u16*)(ws + 67108864);
  u16*   z2b  = (u16*)(ws + 100663296);
  u16*   gpb  = (u16*)(ws + 104857600);
  u16*   wlT  = (u16*)(ws + 146800640);
  u16*   pqqb = (u16*)(ws + 150077440);
  u16*   y0b  = (u16*)(ws + 151388160);
  u16*   w0T  = (u16*)(ws + 168165376);
  u16*   w1T  = (u16*)(ws + 169213952);
  float* S1a  = (float*)(ws + 170262528);
  float* S2a  = S1a + 1024;
  float* S1b  = S2a + 1024;
  float* S2b  = S1b + 512;
  float* cvec = S2b + 512;

  hipMemsetAsync((void*)S1a, 0, 16384, stream);      // S1a,S2a,S1b,S2b,cvec

  k_front<<<13344, 256, 0, stream>>>(fidx, fval, femb, embT, gpb,
                                     wl, wlT, pq, pqqb, w0, w0T, w1, w1T,
                                     pbias, b0, cvec);

  k_prod<<<512, 256, 0, stream>>>(embT, wlT, gpb, pqqb, pbias, y0b);

  // layer 0: z1c (centered bf16) + batch stats; 2048 blocks (8 n-tiles)
  gemm_bt<<<2048, 256, 0, stream>>>(y0b, w0T, z1b, cvec, S1a, S2a,
                                    3, H1_SZ, D_SZ);
  k_bnapply<<<4096, 256, 0, stream>>>(z1b, y1b, S1a, S2a, bnsc, bnof, cvec, 1023);

  // layer 1: z2c (centered bf16) + batch stats; 1024 blocks (4 n-tiles)
  gemm_bt<<<1024, 256, 0, stream>>>(y1b, w1T, z2b, b1, S1b, S2b,
                                    2, H2_SZ, H1_SZ);

  k_out<<<4096, 256, 0, stream>>>(z2b, ow, ob, S1b, S2b, bnsc, bnof, b1, out);
}

// Round 13
// 321.611 us; speedup vs baseline: 1.0355x; 1.0240x over previous
//
#include <hip/hip_runtime.h>

typedef unsigned short u16;
typedef __attribute__((ext_vector_type(8))) short bf16x8v;
typedef __attribute__((ext_vector_type(4))) float f32x4v;

#define B_SZ 16384
#define F_SZ 50
#define E_SZ 64
#define D_SZ 512
#define H1_SZ 1024
#define H2_SZ 512
#define KL 3200   // lz K: k = f*64+e, f<50 -- NO padding (f-major)
#define KG 1280   // gram K: packed upper-tri 1275 -> padded 1280

__device__ __forceinline__ float b2f(u16 u){
  union { unsigned int i; float f; } v; v.i = ((unsigned int)u) << 16; return v.f;
}
__device__ __forceinline__ u16 f2b(float f){
  union { float f; unsigned int i; } v; v.f = f;
  unsigned int r = v.i + 0x7FFFu + ((v.i >> 16) & 1u);
  return (u16)(r >> 16);
}

// async global->LDS, 16B/lane. g is per-lane (base + lane*16B); lds base is
// wave-uniform; HW writes lds_base + lane*16.
__device__ __forceinline__ void gload16(const u16* g, u16* lds_base_uniform){
#if __has_builtin(__builtin_amdgcn_global_load_lds)
  __builtin_amdgcn_global_load_lds(
      (const __attribute__((address_space(1))) unsigned int*)g,
      (__attribute__((address_space(3))) unsigned int*)lds_base_uniform,
      16, 0, 0);
#else
  int lane = threadIdx.x & 63;
  *(uint4*)(lds_base_uniform + lane*8) = *(const uint4*)g;
#endif
}

// XCD-aware grid swizzle (r11: verified FETCH 270->99 MB): blocks sharing an
// A(m)-tile get IDs equal mod 8 -> same XCD L2. x = n-tile, y = m-tile.
__device__ __forceinline__ void swz(int id, int nblog2, int &x, int &y){
  int xcd = id & 7, j = id >> 3;
  x = j & ((1 << nblog2) - 1);
  y = ((j >> nblog2) << 3) | xcd;
}

// ---------------- front kernel v2 (r20, measured best): gather + Gram +
// weight prep. Gather: TWO b per block (halved launch count), embT written
// directly from registers. Ranges:
//   [0,8192)       gather/Gram for b = 2r, 2r+1
//   [8192,8704)    WlT  = bf16(product_linear)
//   [8704,9216)    pqq[d, packed(f,f')] = pq_f*pq_f'*(f==f'?1:2), pad 0
//   [9216,11264)   w0T (N,K) bf16
//   [11264,13312)  w1T (N,K) bf16
//   [13312,13344)  cvec = b0 + pbias @ w0
__global__ __launch_bounds__(256) void k_front(
    const int* __restrict__ fidx, const float* __restrict__ fval,
    const float* __restrict__ femb, u16* __restrict__ embT,
    u16* __restrict__ Gp,
    const float* __restrict__ Wl, u16* __restrict__ WlT,
    const float* __restrict__ Pq, u16* __restrict__ pqq,
    const float* __restrict__ w0, u16* __restrict__ w0T,
    const float* __restrict__ w1, u16* __restrict__ w1T,
    const float* __restrict__ pb, const float* __restrict__ b0,
    float* __restrict__ cvec)
{
  __shared__ int   sidx[2][F_SZ];
  __shared__ float sfv[2][F_SZ];
  __shared__ __align__(16) u16 tile[2][64*72];   // 18 KB (rows 50..63 garbage, masked)
  __shared__ __align__(16) u16 gbuf[2][KG];      // 5 KB
  const int r = blockIdx.x, t = threadIdx.x;
  if (r < 8192){
    const int h  = t >> 7;                 // which b this half-block serves
    const int th = t & 127;
    const int b  = r*2 + h;
    if (th < F_SZ){ sidx[h][th] = fidx[b*F_SZ+th]; sfv[h][th] = fval[b*F_SZ+th]; }
    if (th < 5) gbuf[h][1275+th] = 0;      // zero pad (NaN*0 hazard in MFMA)
    __syncthreads();
    u16* orow = embT + (size_t)b*KL;
    #pragma unroll
    for (int i=0;i<7;i++){
      int k4 = (i*128+th)*4;               // 4 consecutive e, same f
      if (k4 < F_SZ*E_SZ){
        int f = k4>>6, e = k4&63;
        float4 v = *(const float4*)&femb[(size_t)sidx[h][f]*E_SZ + e];
        float s = sfv[h][f];
        u16 q0=f2b(v.x*s), q1=f2b(v.y*s), q2=f2b(v.z*s), q3=f2b(v.w*s);
        tile[h][f*72+e+0]=q0; tile[h][f*72+e+1]=q1;
        tile[h][f*72+e+2]=q2; tile[h][f*72+e+3]=q3;
        union { unsigned long long d; u16 s4[4]; } o4;
        o4.s4[0]=q0; o4.s4[1]=q1; o4.s4[2]=q2; o4.s4[3]=q3;
        *(unsigned long long*)&orow[k4] = o4.d;   // direct 8 B embT store
      }
    }
    __syncthreads();
    // Gram -> gbuf packed upper-tri: idx(m,n) = 50m - m(m-1)/2 + (n-m), n>=m
    const int wave = t >> 6, lane = t & 63, quad = lane >> 4, l16 = lane & 15;
    const int hw = wave >> 1, lw = wave & 1;   // hw: which b, lw: wave-in-pair
    static const int TM[10] = {0,0,0,0,1,1,1,2,2,3};
    static const int TN[10] = {0,1,2,3,1,2,3,2,3,3};
    for (int ti = lw; ti < 10; ti += 2){
      const int tm = TM[ti], tn = TN[ti];
      f32x4v g = {0.f,0.f,0.f,0.f};
      #pragma unroll
      for (int ks=0;ks<2;ks++){
        bf16x8v af = *(const bf16x8v*)&tile[hw][(tm*16+l16)*72 + (ks*4+quad)*8];
        bf16x8v bf = *(const bf16x8v*)&tile[hw][(tn*16+l16)*72 + (ks*4+quad)*8];
        g = __builtin_amdgcn_mfma_f32_16x16x32_bf16(af, bf, g, 0, 0, 0);
      }
      const int gn = tn*16 + l16;          // C/D: n = lane&15, m = quad*4+r
      #pragma unroll
      for (int rr=0;rr<4;rr++){
        const int gm = tm*16 + quad*4 + rr;
        if (gm < F_SZ && gn < F_SZ && gn >= gm)
          gbuf[hw][gm*F_SZ - ((gm*(gm-1))>>1) + (gn-gm)] = f2b(g[rr]);
      }
    }
    __syncthreads();
    if (t < 160){
      #pragma unroll
      for (int hh=0; hh<2; hh++)
        *(uint4*)&Gp[(size_t)(r*2+hh)*KG + t*8] = *(const uint4*)&gbuf[hh][t*8];
    }
  } else if (r < 8704){
    const int d = r - 8192;
    #pragma unroll
    for (int i=0;i<4;i++){
      int k4 = (i*256+t)*4;
      if (k4 < KL){
        float4 v = *(const float4*)&Wl[(size_t)d*KL + k4];
        u16* o = &WlT[(size_t)d*KL + k4];
        o[0]=f2b(v.x); o[1]=f2b(v.y); o[2]=f2b(v.z); o[3]=f2b(v.w);
      }
    }
  } else if (r < 9216){
    const int d = r - 8704;
    const float* prow = &Pq[d*F_SZ];
    u16* orow = &pqq[(size_t)d*KG];
    int trif = 0;
    for (int f=0; f<F_SZ; f++){
      int len = F_SZ - f;
      if (t < len)
        orow[trif + t] = f2b(prow[f]*prow[f+t]*(t ? 2.f : 1.f));
      trif += len;
    }
    if (t < 5) orow[1275+t] = 0;
  } else if (r < 11264){
    int idx = (r-9216)*256 + t;          // 524288
    int k = idx & 511, n = idx >> 9;
    w0T[idx] = f2b(w0[(size_t)k*H1_SZ + n]);
  } else if (r < 13312){
    int idx = (r-11264)*256 + t;         // 524288
    int k = idx & 1023, n = idx >> 10;
    w1T[idx] = f2b(w1[(size_t)k*H2_SZ + n]);
  } else {
    int rr = r - 13312;
    int h = (rr & 3)*256 + t;
    int d0 = (rr >> 2)*64;
    float acc = (d0 == 0) ? b0[h] : 0.f;
    #pragma unroll 8
    for (int d=0; d<64; d++) acc += pb[d0+d]*w0[(size_t)(d0+d)*H1_SZ + h];
    atomicAdd(&cvec[h], acc);
  }
}

// BK=128 XOR-swizzled LDS tiles (r12 proven): rows are 256 B; LDS slot
// (row, block j in [0,16)) holds global block (j XOR (row&7)). Staged by
// lane fetching global block ((lane&15) XOR (row&7)) (4 rows/call);
// fragments read offset ((ks*4+quad) XOR (l16&7))*8.

// ---------------- fused product layer (r17 exact, measured 82.7 us):
// 128m x 128n tile, 64 KB LDS, 2 blocks/CU, 512-block grid, 32x128 wave
// tiles. FROZEN: r19's 64x64 tiles (108.9) and r21-style resizing both
// regressed -- do not change shape.
__global__ __launch_bounds__(256, 2) void k_prod(
    const u16* __restrict__ Ae,    // embT (B, KL)
    const u16* __restrict__ Bw,    // WlT  (D, KL)
    const u16* __restrict__ Ag,    // Gp   (B, KG)
    const u16* __restrict__ Bq,    // pqq  (D, KG)
    const float* __restrict__ pbias,
    u16* __restrict__ y0)          // (B, D)
{
  __shared__ __align__(16) u16 As[128*128];   // 32 KB
  __shared__ __align__(16) u16 Bs[128*128];   // 32 KB
  const int tid  = threadIdx.x;
  const int wave = tid >> 6, lane = tid & 63;
  const int quad = lane >> 4, l16 = lane & 15;
  int bx, by;  swz(blockIdx.x, 2, bx, by);    // 512 blocks: 4 n-tiles, 128 m-tiles
  const int n0 = bx * 128, m0 = by * 128;
  const int lr4 = lane >> 4;
  const int cb  = lane & 15;
  const int sw  = (l16 & 7);

  f32x4v acc1[2][8], acc2[2][8];
  #pragma unroll
  for (int i=0;i<2;i++)
    #pragma unroll
    for (int j=0;j<8;j++){
      acc1[i][j] = (f32x4v){0.f,0.f,0.f,0.f};
      acc2[i][j] = (f32x4v){0.f,0.f,0.f,0.f};
    }

  auto run = [&](const u16* Ap, const u16* Bp, int K, f32x4v (&acc)[2][8]){
    for (int k0 = 0; k0 < K; k0 += 128){
      __syncthreads();
      #pragma unroll
      for (int c=0;c<8;c++){
        const int r0 = wave*32 + c*4;
        const int row = r0 + lr4;
        gload16(Ap + (size_t)(m0 + row)*K + k0 + ((cb ^ (row & 7)) << 3), As + r0*128);
      }
      #pragma unroll
      for (int c=0;c<8;c++){
        const int r0 = wave*32 + c*4;
        const int row = r0 + lr4;
        gload16(Bp + (size_t)(n0 + row)*K + k0 + ((cb ^ (row & 7)) << 3), Bs + r0*128);
      }
      __syncthreads();
      #pragma unroll
      for (int ks=0; ks<4; ks++){
        bf16x8v af[2], bfr[8];
        #pragma unroll
        for (int mt=0;mt<2;mt++)
          af[mt] = *(const bf16x8v*)&As[(wave*32+mt*16+l16)*128 + (((ks*4+quad) ^ sw))*8];
        #pragma unroll
        for (int nt=0;nt<8;nt++)
          bfr[nt] = *(const bf16x8v*)&Bs[(nt*16+l16)*128 + (((ks*4+quad) ^ sw))*8];
        #pragma unroll
        for (int mt=0;mt<2;mt++)
          #pragma unroll
          for (int nt=0;nt<8;nt++)
            acc[mt][nt] = __builtin_amdgcn_mfma_f32_16x16x32_bf16(af[mt], bfr[nt], acc[mt][nt], 0, 0, 0);
      }
    }
  };

  run(Ae, Bw, KL, acc1);     // lz
  run(Ag, Bq, KG, acc2);     // lp^2

  #pragma unroll
  for (int nt=0;nt<8;nt++){
    const int n = n0 + nt*16 + l16;
    const float bv = pbias[n];
    #pragma unroll
    for (int mt=0;mt<2;mt++){
      const int mb = m0 + wave*32 + mt*16 + quad*4;
      #pragma unroll
      for (int r=0;r<4;r++){
        float v = acc1[mt][nt][r] + sqrtf(fmaxf(acc2[mt][nt][r], 0.f)) + bv;
        v = (v > 0.f ? v : 0.f) - bv;
        y0[(size_t)(mb+r)*D_SZ + n] = f2b(v);
      }
    }
  }
}

// ---------------- BT GEMM v3 (r12 exact, FROZEN): BK=128, 64m x 128n,
// 256 threads, 48 KB LDS (3 blocks/CU). r21's 128m variant regressed
// (+9.4 us) -- B-staging is L2-resident and was never the constraint.
// Stats over v = acc+bias[n]; store centered acc (pre-bias) as bf16.
__global__ __launch_bounds__(256) void gemm_bt(
    const u16* __restrict__ A, const u16* __restrict__ Bm,
    u16* __restrict__ C, const float* __restrict__ bias,
    float* __restrict__ S1, float* __restrict__ S2,
    int nblog2, int N, int K)
{
  __shared__ __align__(16) u16 As[64*128];    // 16 KB
  __shared__ __align__(16) u16 Bs[128*128];   // 32 KB
  const int tid  = threadIdx.x;
  const int wave = tid >> 6, lane = tid & 63;
  const int quad = lane >> 4, l16 = lane & 15;
  int bx, by;  swz(blockIdx.x, nblog2, bx, by);
  const int n0 = bx * 128, m0 = by * 64;
  const int wr = wave >> 1, wc = wave & 1;
  const int lr4 = lane >> 4;
  const int cb  = lane & 15;
  const int sw  = (l16 & 7);

  f32x4v acc[2][4];
  #pragma unroll
  for (int i=0;i<2;i++)
    #pragma unroll
    for (int j=0;j<4;j++)
      acc[i][j] = (f32x4v){0.f,0.f,0.f,0.f};

  for (int k0 = 0; k0 < K; k0 += 128){
    __syncthreads();
    #pragma unroll
    for (int c=0;c<4;c++){
      const int r0 = wave*16 + c*4;
      const int row = r0 + lr4;
      gload16(A + (size_t)(m0 + row)*K + k0 + ((cb ^ (row & 7)) << 3), As + r0*128);
    }
    #pragma unroll
    for (int c=0;c<8;c++){
      const int r0 = wave*32 + c*4;
      const int row = r0 + lr4;
      gload16(Bm + (size_t)(n0 + row)*K + k0 + ((cb ^ (row & 7)) << 3), Bs + r0*128);
    }
    __syncthreads();
    #pragma unroll
    for (int ks=0; ks<4; ks++){
      bf16x8v af[2], bfr[4];
      #pragma unroll
      for (int mt=0;mt<2;mt++)
        af[mt] = *(const bf16x8v*)&As[(wr*32+mt*16+l16)*128 + (((ks*4+quad) ^ sw))*8];
      #pragma unroll
      for (int nt=0;nt<4;nt++)
        bfr[nt] = *(const bf16x8v*)&Bs[(wc*64+nt*16+l16)*128 + (((ks*4+quad) ^ sw))*8];
      #pragma unroll
      for (int mt=0;mt<2;mt++)
        #pragma unroll
        for (int nt=0;nt<4;nt++)
          acc[mt][nt] = __builtin_amdgcn_mfma_f32_16x16x32_bf16(af[mt], bfr[nt], acc[mt][nt], 0, 0, 0);
    }
  }

  // epilogue; C/D layout: n = lane&15, m = quad*4 + reg
  #pragma unroll
  for (int nt=0;nt<4;nt++){
    const int n = n0 + wc*64 + nt*16 + l16;
    const float bv = bias[n];
    float ls1 = 0.f, ls2 = 0.f;
    #pragma unroll
    for (int mt=0;mt<2;mt++){
      const int mb = m0 + wr*32 + mt*16 + quad*4;
      #pragma unroll
      for (int r=0;r<4;r++){
        float v = acc[mt][nt][r] + bv;
        C[(size_t)(mb+r)*N + n] = f2b(acc[mt][nt][r]);   // centered store
        ls1 += v; ls2 += v*v;
      }
    }
    ls1 += __shfl_xor(ls1, 16); ls2 += __shfl_xor(ls2, 16);
    ls1 += __shfl_xor(ls1, 32); ls2 += __shfl_xor(ls2, 32);
    if (quad == 0){ atomicAdd(&S1[n], ls1); atomicAdd(&S2[n], ls2); }
  }
}

// ---------------- BN apply + relu with inlined stats finalize (r17/r20
// exact, 8 elems/thread -- r22's 16/thread variant was neutral-to-negative):
// bf16 centered Z in, bf16 Y out. Stored z is (z_full - cadd):
// b = bnof - m*a + a*cadd[n].
__global__ __launch_bounds__(256) void k_bnapply(
    const u16* __restrict__ Z, u16* __restrict__ Y,
    const float* __restrict__ S1, const float* __restrict__ S2,
    const float* __restrict__ bnsc, const float* __restrict__ bnof,
    const float* __restrict__ cadd, int nmask)
{
  size_t base = ((size_t)blockIdx.x*256 + threadIdx.x) * 8;
  int n0 = (int)(base & (size_t)nmask);
  const float invB = 1.f / 16384.f;
  const float sc = bnsc[0], of = bnof[0];
  union { uint4 q; u16 s[8]; } z, o;
  z.q = *(const uint4*)&Z[base];
  #pragma unroll
  for (int j=0;j<8;j++){
    int n = n0 + j;
    float m   = S1[n]*invB;
    float var = S2[n]*invB - m*m;
    float a   = sc * rsqrtf(var + 1e-10f);
    float bb  = of - m*a + a*cadd[n];
    float v = b2f(z.s[j]) * a + bb;
    o.s[j] = f2b(v > 0.f ? v : 0.f);
  }
  *(uint4*)&Y[base] = o.q;
}

// ---------------- final: inlined BN finalize + relu + dot + sigmoid (r17).
__global__ __launch_bounds__(256) void k_out(
    const u16* __restrict__ Z2, const float* __restrict__ wvec,
    const float* __restrict__ obp,
    const float* __restrict__ S1, const float* __restrict__ S2,
    const float* __restrict__ bnsc, const float* __restrict__ bnof,
    const float* __restrict__ cadd,
    float* __restrict__ out)
{
  const int wave = threadIdx.x >> 6, lane = threadIdx.x & 63;
  const int b = blockIdx.x*4 + wave;
  const int n0 = lane*8;
  const float invB = 1.f / 16384.f;
  const float sc = bnsc[0], of = bnof[0];
  union { uint4 q; u16 s[8]; } z;
  z.q = *(const uint4*)&Z2[(size_t)b*H2_SZ + n0];
  float4 wa = *(const float4*)&wvec[n0];
  float4 wb = *(const float4*)&wvec[n0+4];
  float wv[8] = {wa.x,wa.y,wa.z,wa.w,wb.x,wb.y,wb.z,wb.w};
  float s = 0.f;
  #pragma unroll
  for (int j=0;j<8;j++){
    int n = n0 + j;
    float m   = S1[n]*invB;
    float var = S2[n]*invB - m*m;
    float a   = sc * rsqrtf(var + 1e-10f);
    float bb  = of - m*a + a*cadd[n];
    float y = b2f(z.s[j]) * a + bb;
    y = y > 0.f ? y : 0.f;
    s += y * wv[j];
  }
  s += __shfl_xor(s,1);  s += __shfl_xor(s,2);  s += __shfl_xor(s,4);
  s += __shfl_xor(s,8);  s += __shfl_xor(s,16); s += __shfl_xor(s,32);
  if (lane == 0){
    float x = s + obp[0];
    out[b] = 1.f / (1.f + expf(-x));
  }
}

// ---------------- workspace map (bytes) ----------------
// embT @ 0          : 104857600  (B x 3200 bf16; dead after k_prod; reused:)
//   z1c @ 0         :  33554432  (bf16 centered pre-BN layer0)
//   y1  @ 67108864  :  33554432  (bf16 post-BN layer0)
//   z2c @ 100663296 :  16777216  (bf16 centered pre-BN layer1)
// Gp   @ 104857600  :  41943040  (B x 1280 bf16; dead after k_prod)
// WlT  @ 146800640  :   3276800
// pqq  @ 150077440  :   1310720
// y0   @ 151388160  :  16777216  (bf16, bias-centered)
// W0T  @ 168165376  :   1048576
// W1T  @ 169213952  :   1048576
// stats@ 170262528  : 16 KB ZEROED: S1a[1024] S2a[1024] S1b[512] S2b[512] cvec[1024]
// total ~ 170.3 MB

extern "C" void kernel_launch(void* const* d_in, const int* in_sizes, int n_in,
                              void* d_out, int out_size, void* d_ws, size_t ws_size,
                              hipStream_t stream)
{
  const int*   fidx  = (const int*)d_in[0];
  const float* fval  = (const float*)d_in[1];
  const float* femb  = (const float*)d_in[2];
  const float* wl    = (const float*)d_in[3];
  const float* pbias = (const float*)d_in[4];
  const float* pq    = (const float*)d_in[5];
  const float* w0    = (const float*)d_in[6];
  const float* b0    = (const float*)d_in[7];
  const float* w1    = (const float*)d_in[8];
  const float* b1    = (const float*)d_in[9];
  const float* bnsc  = (const float*)d_in[10];
  const float* bnof  = (const float*)d_in[11];
  const float* ow    = (const float*)d_in[12];
  const float* ob    = (const float*)d_in[13];
  float* out = (float*)d_out;

  char* ws = (char*)d_ws;
  u16*   embT = (u16*)(ws + 0);
  u16*   z1b  = (u16*)(ws + 0);
  u16*   y1b  = (u16*)(ws + 67108864);
  u16*   z2b  = (u16*)(ws + 100663296);
  u16*   gpb  = (u16*)(ws + 104857600);
  u16*   wlT  = (u16*)(ws + 146800640);
  u16*   pqqb = (u16*)(ws + 150077440);
  u16*   y0b  = (u16*)(ws + 151388160);
  u16*   w0T  = (u16*)(ws + 168165376);
  u16*   w1T  = (u16*)(ws + 169213952);
  float* S1a  = (float*)(ws + 170262528);
  float* S2a  = S1a + 1024;
  float* S1b  = S2a + 1024;
  float* S2b  = S1b + 512;
  float* cvec = S2b + 512;

  hipMemsetAsync((void*)S1a, 0, 16384, stream);      // S1a,S2a,S1b,S2b,cvec

  k_front<<<13344, 256, 0, stream>>>(fidx, fval, femb, embT, gpb,
                                     wl, wlT, pq, pqqb, w0, w0T, w1, w1T,
                                     pbias, b0, cvec);

  k_prod<<<512, 256, 0, stream>>>(embT, wlT, gpb, pqqb, pbias, y0b);

  // layer 0: z1c (centered bf16) + batch stats; 2048 blocks (8 n-tiles)
  gemm_bt<<<2048, 256, 0, stream>>>(y0b, w0T, z1b, cvec, S1a, S2a,
                                    3, H1_SZ, D_SZ);
  k_bnapply<<<8192, 256, 0, stream>>>(z1b, y1b, S1a, S2a, bnsc, bnof, cvec, 1023);

  // layer 1: z2c (centered bf16) + batch stats; 1024 blocks (4 n-tiles)
  gemm_bt<<<1024, 256, 0, stream>>>(y1b, w1T, z2b, b1, S1b, S2b,
                                    2, H2_SZ, H1_SZ);

  k_out<<<4096, 256, 0, stream>>>(z2b, ow, ob, S1b, S2b, bnsc, bnof, b1, out);
}

// Round 14
// 319.423 us; speedup vs baseline: 1.0426x; 1.0068x over previous
//
#include <hip/hip_runtime.h>

typedef unsigned short u16;
typedef __attribute__((ext_vector_type(8))) short bf16x8v;
typedef __attribute__((ext_vector_type(4))) float f32x4v;

#define B_SZ 16384
#define F_SZ 50
#define E_SZ 64
#define D_SZ 512
#define H1_SZ 1024
#define H2_SZ 512
#define KL 3200   // lz K: k = f*64+e, f<50 -- NO padding (f-major)
#define KG 1280   // gram K: packed upper-tri 1275 -> padded 1280

__device__ __forceinline__ float b2f(u16 u){
  union { unsigned int i; float f; } v; v.i = ((unsigned int)u) << 16; return v.f;
}
__device__ __forceinline__ u16 f2b(float f){
  union { float f; unsigned int i; } v; v.f = f;
  unsigned int r = v.i + 0x7FFFu + ((v.i >> 16) & 1u);
  return (u16)(r >> 16);
}

// async global->LDS, 16B/lane. g is per-lane (base + lane*16B); lds base is
// wave-uniform; HW writes lds_base + lane*16.
__device__ __forceinline__ void gload16(const u16* g, u16* lds_base_uniform){
#if __has_builtin(__builtin_amdgcn_global_load_lds)
  __builtin_amdgcn_global_load_lds(
      (const __attribute__((address_space(1))) unsigned int*)g,
      (__attribute__((address_space(3))) unsigned int*)lds_base_uniform,
      16, 0, 0);
#else
  int lane = threadIdx.x & 63;
  *(uint4*)(lds_base_uniform + lane*8) = *(const uint4*)g;
#endif
}

// XCD-aware grid swizzle (r11: verified FETCH 270->99 MB): blocks sharing an
// A(m)-tile get IDs equal mod 8 -> same XCD L2. x = n-tile, y = m-tile.
__device__ __forceinline__ void swz(int id, int nblog2, int &x, int &y){
  int xcd = id & 7, j = id >> 3;
  x = j & ((1 << nblog2) - 1);
  y = ((j >> nblog2) << 3) | xcd;
}

// ---------------- front kernel v2 (r20, measured best): gather + Gram +
// weight prep. Gather: TWO b per block, embT written directly from regs.
__global__ __launch_bounds__(256) void k_front(
    const int* __restrict__ fidx, const float* __restrict__ fval,
    const float* __restrict__ femb, u16* __restrict__ embT,
    u16* __restrict__ Gp,
    const float* __restrict__ Wl, u16* __restrict__ WlT,
    const float* __restrict__ Pq, u16* __restrict__ pqq,
    const float* __restrict__ w0, u16* __restrict__ w0T,
    const float* __restrict__ w1, u16* __restrict__ w1T,
    const float* __restrict__ pb, const float* __restrict__ b0,
    float* __restrict__ cvec)
{
  __shared__ int   sidx[2][F_SZ];
  __shared__ float sfv[2][F_SZ];
  __shared__ __align__(16) u16 tile[2][64*72];   // rows 50..63 garbage, masked
  __shared__ __align__(16) u16 gbuf[2][KG];
  const int r = blockIdx.x, t = threadIdx.x;
  if (r < 8192){
    const int h  = t >> 7;
    const int th = t & 127;
    const int b  = r*2 + h;
    if (th < F_SZ){ sidx[h][th] = fidx[b*F_SZ+th]; sfv[h][th] = fval[b*F_SZ+th]; }
    if (th < 5) gbuf[h][1275+th] = 0;      // zero pad (NaN*0 hazard in MFMA)
    __syncthreads();
    u16* orow = embT + (size_t)b*KL;
    #pragma unroll
    for (int i=0;i<7;i++){
      int k4 = (i*128+th)*4;               // 4 consecutive e, same f
      if (k4 < F_SZ*E_SZ){
        int f = k4>>6, e = k4&63;
        float4 v = *(const float4*)&femb[(size_t)sidx[h][f]*E_SZ + e];
        float s = sfv[h][f];
        u16 q0=f2b(v.x*s), q1=f2b(v.y*s), q2=f2b(v.z*s), q3=f2b(v.w*s);
        tile[h][f*72+e+0]=q0; tile[h][f*72+e+1]=q1;
        tile[h][f*72+e+2]=q2; tile[h][f*72+e+3]=q3;
        union { unsigned long long d; u16 s4[4]; } o4;
        o4.s4[0]=q0; o4.s4[1]=q1; o4.s4[2]=q2; o4.s4[3]=q3;
        *(unsigned long long*)&orow[k4] = o4.d;   // direct 8 B embT store
      }
    }
    __syncthreads();
    // Gram -> gbuf packed upper-tri: idx(m,n) = 50m - m(m-1)/2 + (n-m), n>=m
    const int wave = t >> 6, lane = t & 63, quad = lane >> 4, l16 = lane & 15;
    const int hw = wave >> 1, lw = wave & 1;
    static const int TM[10] = {0,0,0,0,1,1,1,2,2,3};
    static const int TN[10] = {0,1,2,3,1,2,3,2,3,3};
    for (int ti = lw; ti < 10; ti += 2){
      const int tm = TM[ti], tn = TN[ti];
      f32x4v g = {0.f,0.f,0.f,0.f};
      #pragma unroll
      for (int ks=0;ks<2;ks++){
        bf16x8v af = *(const bf16x8v*)&tile[hw][(tm*16+l16)*72 + (ks*4+quad)*8];
        bf16x8v bf = *(const bf16x8v*)&tile[hw][(tn*16+l16)*72 + (ks*4+quad)*8];
        g = __builtin_amdgcn_mfma_f32_16x16x32_bf16(af, bf, g, 0, 0, 0);
      }
      const int gn = tn*16 + l16;          // C/D: n = lane&15, m = quad*4+r
      #pragma unroll
      for (int rr=0;rr<4;rr++){
        const int gm = tm*16 + quad*4 + rr;
        if (gm < F_SZ && gn < F_SZ && gn >= gm)
          gbuf[hw][gm*F_SZ - ((gm*(gm-1))>>1) + (gn-gm)] = f2b(g[rr]);
      }
    }
    __syncthreads();
    if (t < 160){
      #pragma unroll
      for (int hh=0; hh<2; hh++)
        *(uint4*)&Gp[(size_t)(r*2+hh)*KG + t*8] = *(const uint4*)&gbuf[hh][t*8];
    }
  } else if (r < 8704){
    const int d = r - 8192;
    #pragma unroll
    for (int i=0;i<4;i++){
      int k4 = (i*256+t)*4;
      if (k4 < KL){
        float4 v = *(const float4*)&Wl[(size_t)d*KL + k4];
        u16* o = &WlT[(size_t)d*KL + k4];
        o[0]=f2b(v.x); o[1]=f2b(v.y); o[2]=f2b(v.z); o[3]=f2b(v.w);
      }
    }
  } else if (r < 9216){
    const int d = r - 8704;
    const float* prow = &Pq[d*F_SZ];
    u16* orow = &pqq[(size_t)d*KG];
    int trif = 0;
    for (int f=0; f<F_SZ; f++){
      int len = F_SZ - f;
      if (t < len)
        orow[trif + t] = f2b(prow[f]*prow[f+t]*(t ? 2.f : 1.f));
      trif += len;
    }
    if (t < 5) orow[1275+t] = 0;
  } else if (r < 11264){
    int idx = (r-9216)*256 + t;          // 524288
    int k = idx & 511, n = idx >> 9;
    w0T[idx] = f2b(w0[(size_t)k*H1_SZ + n]);
  } else if (r < 13312){
    int idx = (r-11264)*256 + t;         // 524288
    int k = idx & 1023, n = idx >> 10;
    w1T[idx] = f2b(w1[(size_t)k*H2_SZ + n]);
  } else {
    int rr = r - 13312;
    int h = (rr & 3)*256 + t;
    int d0 = (rr >> 2)*64;
    float acc = (d0 == 0) ? b0[h] : 0.f;
    #pragma unroll 8
    for (int d=0; d<64; d++) acc += pb[d0+d]*w0[(size_t)(d0+d)*H1_SZ + h];
    atomicAdd(&cvec[h], acc);
  }
}

// BK=128 XOR-swizzled LDS tiles (r12 proven): rows are 256 B; LDS slot
// (row, block j in [0,16)) holds global block (j XOR (row&7)). Staged by
// lane fetching global block ((lane&15) XOR (row&7)) (4 rows/call);
// fragments read offset ((ks*4+quad) XOR (l16&7))*8.

// ---------------- fused product layer (r17 exact, FROZEN): 128m x 128n,
// 64 KB LDS, 2 blocks/CU, 512-block grid, 32x128 wave tiles.
__global__ __launch_bounds__(256, 2) void k_prod(
    const u16* __restrict__ Ae,    // embT (B, KL)
    const u16* __restrict__ Bw,    // WlT  (D, KL)
    const u16* __restrict__ Ag,    // Gp   (B, KG)
    const u16* __restrict__ Bq,    // pqq  (D, KG)
    const float* __restrict__ pbias,
    u16* __restrict__ y0)          // (B, D)
{
  __shared__ __align__(16) u16 As[128*128];   // 32 KB
  __shared__ __align__(16) u16 Bs[128*128];   // 32 KB
  const int tid  = threadIdx.x;
  const int wave = tid >> 6, lane = tid & 63;
  const int quad = lane >> 4, l16 = lane & 15;
  int bx, by;  swz(blockIdx.x, 2, bx, by);    // 512 blocks: 4 n-tiles, 128 m-tiles
  const int n0 = bx * 128, m0 = by * 128;
  const int lr4 = lane >> 4;
  const int cb  = lane & 15;
  const int sw  = (l16 & 7);

  f32x4v acc1[2][8], acc2[2][8];
  #pragma unroll
  for (int i=0;i<2;i++)
    #pragma unroll
    for (int j=0;j<8;j++){
      acc1[i][j] = (f32x4v){0.f,0.f,0.f,0.f};
      acc2[i][j] = (f32x4v){0.f,0.f,0.f,0.f};
    }

  auto run = [&](const u16* Ap, const u16* Bp, int K, f32x4v (&acc)[2][8]){
    for (int k0 = 0; k0 < K; k0 += 128){
      __syncthreads();
      #pragma unroll
      for (int c=0;c<8;c++){
        const int r0 = wave*32 + c*4;
        const int row = r0 + lr4;
        gload16(Ap + (size_t)(m0 + row)*K + k0 + ((cb ^ (row & 7)) << 3), As + r0*128);
      }
      #pragma unroll
      for (int c=0;c<8;c++){
        const int r0 = wave*32 + c*4;
        const int row = r0 + lr4;
        gload16(Bp + (size_t)(n0 + row)*K + k0 + ((cb ^ (row & 7)) << 3), Bs + r0*128);
      }
      __syncthreads();
      #pragma unroll
      for (int ks=0; ks<4; ks++){
        bf16x8v af[2], bfr[8];
        #pragma unroll
        for (int mt=0;mt<2;mt++)
          af[mt] = *(const bf16x8v*)&As[(wave*32+mt*16+l16)*128 + (((ks*4+quad) ^ sw))*8];
        #pragma unroll
        for (int nt=0;nt<8;nt++)
          bfr[nt] = *(const bf16x8v*)&Bs[(nt*16+l16)*128 + (((ks*4+quad) ^ sw))*8];
        #pragma unroll
        for (int mt=0;mt<2;mt++)
          #pragma unroll
          for (int nt=0;nt<8;nt++)
            acc[mt][nt] = __builtin_amdgcn_mfma_f32_16x16x32_bf16(af[mt], bfr[nt], acc[mt][nt], 0, 0, 0);
      }
    }
  };

  run(Ae, Bw, KL, acc1);     // lz
  run(Ag, Bq, KG, acc2);     // lp^2

  #pragma unroll
  for (int nt=0;nt<8;nt++){
    const int n = n0 + nt*16 + l16;
    const float bv = pbias[n];
    #pragma unroll
    for (int mt=0;mt<2;mt++){
      const int mb = m0 + wave*32 + mt*16 + quad*4;
      #pragma unroll
      for (int r=0;r<4;r++){
        float v = acc1[mt][nt][r] + sqrtf(fmaxf(acc2[mt][nt][r], 0.f)) + bv;
        v = (v > 0.f ? v : 0.f) - bv;
        y0[(size_t)(mb+r)*D_SZ + n] = f2b(v);
      }
    }
  }
}

// ---------------- BT GEMM v3 (r12 exact, FROZEN): BK=128, 64m x 128n,
// 48 KB LDS (3 blocks/CU). Stats over v = acc+bias[n]; store centered acc.
__global__ __launch_bounds__(256) void gemm_bt(
    const u16* __restrict__ A, const u16* __restrict__ Bm,
    u16* __restrict__ C, const float* __restrict__ bias,
    float* __restrict__ S1, float* __restrict__ S2,
    int nblog2, int N, int K)
{
  __shared__ __align__(16) u16 As[64*128];    // 16 KB
  __shared__ __align__(16) u16 Bs[128*128];   // 32 KB
  const int tid  = threadIdx.x;
  const int wave = tid >> 6, lane = tid & 63;
  const int quad = lane >> 4, l16 = lane & 15;
  int bx, by;  swz(blockIdx.x, nblog2, bx, by);
  const int n0 = bx * 128, m0 = by * 64;
  const int wr = wave >> 1, wc = wave & 1;
  const int lr4 = lane >> 4;
  const int cb  = lane & 15;
  const int sw  = (l16 & 7);

  f32x4v acc[2][4];
  #pragma unroll
  for (int i=0;i<2;i++)
    #pragma unroll
    for (int j=0;j<4;j++)
      acc[i][j] = (f32x4v){0.f,0.f,0.f,0.f};

  for (int k0 = 0; k0 < K; k0 += 128){
    __syncthreads();
    #pragma unroll
    for (int c=0;c<4;c++){
      const int r0 = wave*16 + c*4;
      const int row = r0 + lr4;
      gload16(A + (size_t)(m0 + row)*K + k0 + ((cb ^ (row & 7)) << 3), As + r0*128);
    }
    #pragma unroll
    for (int c=0;c<8;c++){
      const int r0 = wave*32 + c*4;
      const int row = r0 + lr4;
      gload16(Bm + (size_t)(n0 + row)*K + k0 + ((cb ^ (row & 7)) << 3), Bs + r0*128);
    }
    __syncthreads();
    #pragma unroll
    for (int ks=0; ks<4; ks++){
      bf16x8v af[2], bfr[4];
      #pragma unroll
      for (int mt=0;mt<2;mt++)
        af[mt] = *(const bf16x8v*)&As[(wr*32+mt*16+l16)*128 + (((ks*4+quad) ^ sw))*8];
      #pragma unroll
      for (int nt=0;nt<4;nt++)
        bfr[nt] = *(const bf16x8v*)&Bs[(wc*64+nt*16+l16)*128 + (((ks*4+quad) ^ sw))*8];
      #pragma unroll
      for (int mt=0;mt<2;mt++)
        #pragma unroll
        for (int nt=0;nt<4;nt++)
          acc[mt][nt] = __builtin_amdgcn_mfma_f32_16x16x32_bf16(af[mt], bfr[nt], acc[mt][nt], 0, 0, 0);
    }
  }

  // epilogue; C/D layout: n = lane&15, m = quad*4 + reg
  #pragma unroll
  for (int nt=0;nt<4;nt++){
    const int n = n0 + wc*64 + nt*16 + l16;
    const float bv = bias[n];
    float ls1 = 0.f, ls2 = 0.f;
    #pragma unroll
    for (int mt=0;mt<2;mt++){
      const int mb = m0 + wr*32 + mt*16 + quad*4;
      #pragma unroll
      for (int r=0;r<4;r++){
        float v = acc[mt][nt][r] + bv;
        C[(size_t)(mb+r)*N + n] = f2b(acc[mt][nt][r]);   // centered store
        ls1 += v; ls2 += v*v;
      }
    }
    ls1 += __shfl_xor(ls1, 16); ls2 += __shfl_xor(ls2, 16);
    ls1 += __shfl_xor(ls1, 32); ls2 += __shfl_xor(ls2, 32);
    if (quad == 0){ atomicAdd(&S1[n], ls1); atomicAdd(&S2[n], ls2); }
  }
}

// ---------------- BN finalize (r23, layer-0): per-column a, b for gemm_bn.
// Stored z1 is (z_full - cvec): b = bnof - m*a + a*cvec[n].
__global__ void k_bnfin(const float* __restrict__ S1, const float* __restrict__ S2,
                        const float* __restrict__ bnsc, const float* __restrict__ bnof,
                        const float* __restrict__ cadd,
                        float* __restrict__ Aout, float* __restrict__ Bout)
{
  int i = blockIdx.x*256 + threadIdx.x;
  const float invB = 1.f / 16384.f;
  float m   = S1[i]*invB;
  float var = S2[i]*invB - m*m;
  float a   = bnsc[0] * rsqrtf(var + 1e-10f);
  Aout[i] = a;
  Bout[i] = bnof[0] - m*a + a*cadd[i];
}

// ---------------- layer-1 GEMM, BN+relu fused via T14 split (r23).
// vs r18 (which exposed A-latency serially and regressed): chunk t+1's A
// global loads are ISSUED right after the barrier, so their HBM/L2 latency
// hides under chunk t's 16-MFMA cluster; the convert (relu(z*a+b) -> bf16)
// and ds_write to the swizzled slot happen at the TOP of iteration t+1, when
// the data has long arrived. Same geometry/swizzle/epilogue as gemm_bt
// (64m x 128n, BK=128, 48 KB LDS, 3 blocks/CU). y1 values are bit-identical
// to the old k_bnapply path (same formula, same f2b rounding). Kills
// k_bnapply (~13 us) + the y1 HBM round-trip (67 MB).
__global__ __launch_bounds__(256) void gemm_bn(
    const u16* __restrict__ Z,     // z1c (B, 1024) centered bf16
    const u16* __restrict__ Bm,    // w1T (512, 1024)
    const float* __restrict__ Aa, const float* __restrict__ Bb,
    u16* __restrict__ C,           // z2c (B, 512) centered
    const float* __restrict__ bias,
    float* __restrict__ S1, float* __restrict__ S2)
{
  __shared__ __align__(16) u16 As[64*128];    // 16 KB
  __shared__ __align__(16) u16 Bs[128*128];   // 32 KB
  const int tid  = threadIdx.x;
  const int wave = tid >> 6, lane = tid & 63;
  const int quad = lane >> 4, l16 = lane & 15;
  int bx, by;  swz(blockIdx.x, 2, bx, by);    // 4 n-tiles, 256 m-tiles
  const int n0 = bx * 128, m0 = by * 64;
  const int wr = wave >> 1, wc = wave & 1;
  const int lr4 = lane >> 4;
  const int cb  = lane & 15;
  const int sw  = (l16 & 7);

  f32x4v acc[2][4];
  #pragma unroll
  for (int i=0;i<2;i++)
    #pragma unroll
    for (int j=0;j<4;j++)
      acc[i][j] = (f32x4v){0.f,0.f,0.f,0.f};

  uint4 zA[4];
  auto loadA = [&](int k0){
    #pragma unroll
    for (int c=0;c<4;c++){
      const int row = wave*16 + c*4 + lr4;
      const int col = k0 + ((cb ^ (row & 7)) << 3);
      zA[c] = *(const uint4*)&Z[(size_t)(m0 + row)*H1_SZ + col];
    }
  };

  loadA(0);                          // prologue: A-chunk 0 in flight
  for (int t = 0; t < 8; ++t){       // K = 1024, BK = 128
    const int k0 = t*128;
    __syncthreads();                 // LDS from chunk t-1 fully consumed
    // convert + write A (data arrived during previous MFMA phase)
    #pragma unroll
    for (int c=0;c<4;c++){
      const int row = wave*16 + c*4 + lr4;
      const int col = k0 + ((cb ^ (row & 7)) << 3);
      float4 a0 = *(const float4*)&Aa[col];
      float4 a1 = *(const float4*)&Aa[col+4];
      float4 b0 = *(const float4*)&Bb[col];
      float4 b1 = *(const float4*)&Bb[col+4];
      float av[8] = {a0.x,a0.y,a0.z,a0.w,a1.x,a1.y,a1.z,a1.w};
      float bv[8] = {b0.x,b0.y,b0.z,b0.w,b1.x,b1.y,b1.z,b1.w};
      union { uint4 q; u16 s[8]; } z, o;
      z.q = zA[c];
      #pragma unroll
      for (int j=0;j<8;j++){
        float v = b2f(z.s[j]) * av[j] + bv[j];
        o.s[j] = f2b(v > 0.f ? v : 0.f);
      }
      *(uint4*)&As[row*128 + cb*8] = o.q;   // ds_write_b128, swizzled slot
    }
    #pragma unroll
    for (int c=0;c<8;c++){
      const int r0 = wave*32 + c*4;
      const int row = r0 + lr4;
      gload16(Bm + (size_t)(n0 + row)*H1_SZ + k0 + ((cb ^ (row & 7)) << 3), Bs + r0*128);
    }
    __syncthreads();                 // Bs ready, As written
    if (t < 7) loadA(k0 + 128);      // ISSUE EARLY: latency hides under MFMA
    #pragma unroll
    for (int ks=0; ks<4; ks++){
      bf16x8v af[2], bfr[4];
      #pragma unroll
      for (int mt=0;mt<2;mt++)
        af[mt] = *(const bf16x8v*)&As[(wr*32+mt*16+l16)*128 + (((ks*4+quad) ^ sw))*8];
      #pragma unroll
      for (int nt=0;nt<4;nt++)
        bfr[nt] = *(const bf16x8v*)&Bs[(wc*64+nt*16+l16)*128 + (((ks*4+quad) ^ sw))*8];
      #pragma unroll
      for (int mt=0;mt<2;mt++)
        #pragma unroll
        for (int nt=0;nt<4;nt++)
          acc[mt][nt] = __builtin_amdgcn_mfma_f32_16x16x32_bf16(af[mt], bfr[nt], acc[mt][nt], 0, 0, 0);
    }
  }

  // epilogue: store centered acc, stats over acc+b1 (== gemm_bt)
  #pragma unroll
  for (int nt=0;nt<4;nt++){
    const int n = n0 + wc*64 + nt*16 + l16;
    const float bv = bias[n];
    float ls1 = 0.f, ls2 = 0.f;
    #pragma unroll
    for (int mt=0;mt<2;mt++){
      const int mb = m0 + wr*32 + mt*16 + quad*4;
      #pragma unroll
      for (int r=0;r<4;r++){
        float v = acc[mt][nt][r] + bv;
        C[(size_t)(mb+r)*H2_SZ + n] = f2b(acc[mt][nt][r]);
        ls1 += v; ls2 += v*v;
      }
    }
    ls1 += __shfl_xor(ls1, 16); ls2 += __shfl_xor(ls2, 16);
    ls1 += __shfl_xor(ls1, 32); ls2 += __shfl_xor(ls2, 32);
    if (quad == 0){ atomicAdd(&S1[n], ls1); atomicAdd(&S2[n], ls2); }
  }
}

// ---------------- final: inlined BN finalize + relu + dot + sigmoid (r17).
__global__ __launch_bounds__(256) void k_out(
    const u16* __restrict__ Z2, const float* __restrict__ wvec,
    const float* __restrict__ obp,
    const float* __restrict__ S1, const float* __restrict__ S2,
    const float* __restrict__ bnsc, const float* __restrict__ bnof,
    const float* __restrict__ cadd,
    float* __restrict__ out)
{
  const int wave = threadIdx.x >> 6, lane = threadIdx.x & 63;
  const int b = blockIdx.x*4 + wave;
  const int n0 = lane*8;
  const float invB = 1.f / 16384.f;
  const float sc = bnsc[0], of = bnof[0];
  union { uint4 q; u16 s[8]; } z;
  z.q = *(const uint4*)&Z2[(size_t)b*H2_SZ + n0];
  float4 wa = *(const float4*)&wvec[n0];
  float4 wb = *(const float4*)&wvec[n0+4];
  float wv[8] = {wa.x,wa.y,wa.z,wa.w,wb.x,wb.y,wb.z,wb.w};
  float s = 0.f;
  #pragma unroll
  for (int j=0;j<8;j++){
    int n = n0 + j;
    float m   = S1[n]*invB;
    float var = S2[n]*invB - m*m;
    float a   = sc * rsqrtf(var + 1e-10f);
    float bb  = of - m*a + a*cadd[n];
    float y = b2f(z.s[j]) * a + bb;
    y = y > 0.f ? y : 0.f;
    s += y * wv[j];
  }
  s += __shfl_xor(s,1);  s += __shfl_xor(s,2);  s += __shfl_xor(s,4);
  s += __shfl_xor(s,8);  s += __shfl_xor(s,16); s += __shfl_xor(s,32);
  if (lane == 0){
    float x = s + obp[0];
    out[b] = 1.f / (1.f + expf(-x));
  }
}

// ---------------- workspace map (bytes) ----------------
// embT @ 0          : 104857600  (B x 3200 bf16; dead after k_prod; reused:)
//   z1c @ 0         :  33554432  (bf16 centered pre-BN layer0)
//   z2c @ 100663296 :  16777216  (bf16 centered pre-BN layer1)
// Gp   @ 104857600  :  41943040  (B x 1280 bf16; dead after k_prod)
// WlT  @ 146800640  :   3276800
// pqq  @ 150077440  :   1310720
// y0   @ 151388160  :  16777216  (bf16, bias-centered)
// W0T  @ 168165376  :   1048576
// W1T  @ 169213952  :   1048576
// stats@ 170262528  : 16 KB ZEROED: S1a[1024] S2a[1024] S1b[512] S2b[512] cvec[1024]
//      then A0[1024] B0[1024] (fp32, k_bnfin output)
// total ~ 170.3 MB

extern "C" void kernel_launch(void* const* d_in, const int* in_sizes, int n_in,
                              void* d_out, int out_size, void* d_ws, size_t ws_size,
                              hipStream_t stream)
{
  const int*   fidx  = (const int*)d_in[0];
  const float* fval  = (const float*)d_in[1];
  const float* femb  = (const float*)d_in[2];
  const float* wl    = (const float*)d_in[3];
  const float* pbias = (const float*)d_in[4];
  const float* pq    = (const float*)d_in[5];
  const float* w0    = (const float*)d_in[6];
  const float* b0    = (const float*)d_in[7];
  const float* w1    = (const float*)d_in[8];
  const float* b1    = (const float*)d_in[9];
  const float* bnsc  = (const float*)d_in[10];
  const float* bnof  = (const float*)d_in[11];
  const float* ow    = (const float*)d_in[12];
  const float* ob    = (const float*)d_in[13];
  float* out = (float*)d_out;

  char* ws = (char*)d_ws;
  u16*   embT = (u16*)(ws + 0);
  u16*   z1b  = (u16*)(ws + 0);
  u16*   z2b  = (u16*)(ws + 100663296);
  u16*   gpb  = (u16*)(ws + 104857600);
  u16*   wlT  = (u16*)(ws + 146800640);
  u16*   pqqb = (u16*)(ws + 150077440);
  u16*   y0b  = (u16*)(ws + 151388160);
  u16*   w0T  = (u16*)(ws + 168165376);
  u16*   w1T  = (u16*)(ws + 169213952);
  float* S1a  = (float*)(ws + 170262528);
  float* S2a  = S1a + 1024;
  float* S1b  = S2a + 1024;
  float* S2b  = S1b + 512;
  float* cvec = S2b + 512;
  float* A0   = cvec + 1024;
  float* B0   = A0 + 1024;

  hipMemsetAsync((void*)S1a, 0, 16384, stream);      // S1a,S2a,S1b,S2b,cvec

  k_front<<<13344, 256, 0, stream>>>(fidx, fval, femb, embT, gpb,
                                     wl, wlT, pq, pqqb, w0, w0T, w1, w1T,
                                     pbias, b0, cvec);

  k_prod<<<512, 256, 0, stream>>>(embT, wlT, gpb, pqqb, pbias, y0b);

  // layer 0: z1c (centered bf16) + batch stats
  gemm_bt<<<2048, 256, 0, stream>>>(y0b, w0T, z1b, cvec, S1a, S2a,
                                    3, H1_SZ, D_SZ);
  k_bnfin<<<4, 256, 0, stream>>>(S1a, S2a, bnsc, bnof, cvec, A0, B0);

  // layer 1: BN(z1c)+relu fused into A-staging (T14 split); z2c + stats
  gemm_bn<<<1024, 256, 0, stream>>>(z1b, w1T, A0, B0, z2b, b1, S1b, S2b);

  k_out<<<4096, 256, 0, stream>>>(z2b, ow, ob, S1b, S2b, bnsc, bnof, b1, out);
}

// Round 17
// 316.855 us; speedup vs baseline: 1.0510x; 1.0081x over previous
//
#include <hip/hip_runtime.h>

typedef unsigned short u16;
typedef __attribute__((ext_vector_type(8))) short bf16x8v;
typedef __attribute__((ext_vector_type(4))) float f32x4v;

#define B_SZ 16384
#define F_SZ 50
#define E_SZ 64
#define D_SZ 512
#define H1_SZ 1024
#define H2_SZ 512
#define KL 3200   // lz K: k = f*64+e, f<50 -- NO padding (f-major)
#define KG 1280   // gram K: packed upper-tri 1275 -> padded 1280

__device__ __forceinline__ float b2f(u16 u){
  union { unsigned int i; float f; } v; v.i = ((unsigned int)u) << 16; return v.f;
}
__device__ __forceinline__ u16 f2b(float f){
  union { float f; unsigned int i; } v; v.f = f;
  unsigned int r = v.i + 0x7FFFu + ((v.i >> 16) & 1u);
  return (u16)(r >> 16);
}

// async global->LDS, 16B/lane. g is per-lane (base + lane*16B); lds base is
// wave-uniform; HW writes lds_base + lane*16.
__device__ __forceinline__ void gload16(const u16* g, u16* lds_base_uniform){
#if __has_builtin(__builtin_amdgcn_global_load_lds)
  __builtin_amdgcn_global_load_lds(
      (const __attribute__((address_space(1))) unsigned int*)g,
      (__attribute__((address_space(3))) unsigned int*)lds_base_uniform,
      16, 0, 0);
#else
  int lane = threadIdx.x & 63;
  *(uint4*)(lds_base_uniform + lane*8) = *(const uint4*)g;
#endif
}

// XCD-aware grid swizzle (r11: verified FETCH 270->99 MB): blocks sharing an
// A(m)-tile get IDs equal mod 8 -> same XCD L2. x = n-tile, y = m-tile.
__device__ __forceinline__ void swz(int id, int nblog2, int &x, int &y){
  int xcd = id & 7, j = id >> 3;
  x = j & ((1 << nblog2) - 1);
  y = ((j >> nblog2) << 3) | xcd;
}

// ---------------- front kernel v2 (r20, measured best): gather + Gram +
// weight prep. Gather: TWO b per block, embT written directly from regs.
__global__ __launch_bounds__(256) void k_front(
    const int* __restrict__ fidx, const float* __restrict__ fval,
    const float* __restrict__ femb, u16* __restrict__ embT,
    u16* __restrict__ Gp,
    const float* __restrict__ Wl, u16* __restrict__ WlT,
    const float* __restrict__ Pq, u16* __restrict__ pqq,
    const float* __restrict__ w0, u16* __restrict__ w0T,
    const float* __restrict__ w1, u16* __restrict__ w1T,
    const float* __restrict__ pb, const float* __restrict__ b0,
    float* __restrict__ cvec)
{
  __shared__ int   sidx[2][F_SZ];
  __shared__ float sfv[2][F_SZ];
  __shared__ __align__(16) u16 tile[2][64*72];   // rows 50..63 garbage, masked
  __shared__ __align__(16) u16 gbuf[2][KG];
  const int r = blockIdx.x, t = threadIdx.x;
  if (r < 8192){
    const int h  = t >> 7;
    const int th = t & 127;
    const int b  = r*2 + h;
    if (th < F_SZ){ sidx[h][th] = fidx[b*F_SZ+th]; sfv[h][th] = fval[b*F_SZ+th]; }
    if (th < 5) gbuf[h][1275+th] = 0;      // zero pad (NaN*0 hazard in MFMA)
    __syncthreads();
    u16* orow = embT + (size_t)b*KL;
    #pragma unroll
    for (int i=0;i<7;i++){
      int k4 = (i*128+th)*4;               // 4 consecutive e, same f
      if (k4 < F_SZ*E_SZ){
        int f = k4>>6, e = k4&63;
        float4 v = *(const float4*)&femb[(size_t)sidx[h][f]*E_SZ + e];
        float s = sfv[h][f];
        u16 q0=f2b(v.x*s), q1=f2b(v.y*s), q2=f2b(v.z*s), q3=f2b(v.w*s);
        tile[h][f*72+e+0]=q0; tile[h][f*72+e+1]=q1;
        tile[h][f*72+e+2]=q2; tile[h][f*72+e+3]=q3;
        union { unsigned long long d; u16 s4[4]; } o4;
        o4.s4[0]=q0; o4.s4[1]=q1; o4.s4[2]=q2; o4.s4[3]=q3;
        *(unsigned long long*)&orow[k4] = o4.d;   // direct 8 B embT store
      }
    }
    __syncthreads();
    // Gram -> gbuf packed upper-tri: idx(m,n) = 50m - m(m-1)/2 + (n-m), n>=m
    const int wave = t >> 6, lane = t & 63, quad = lane >> 4, l16 = lane & 15;
    const int hw = wave >> 1, lw = wave & 1;
    static const int TM[10] = {0,0,0,0,1,1,1,2,2,3};
    static const int TN[10] = {0,1,2,3,1,2,3,2,3,3};
    for (int ti = lw; ti < 10; ti += 2){
      const int tm = TM[ti], tn = TN[ti];
      f32x4v g = {0.f,0.f,0.f,0.f};
      #pragma unroll
      for (int ks=0;ks<2;ks++){
        bf16x8v af = *(const bf16x8v*)&tile[hw][(tm*16+l16)*72 + (ks*4+quad)*8];
        bf16x8v bf = *(const bf16x8v*)&tile[hw][(tn*16+l16)*72 + (ks*4+quad)*8];
        g = __builtin_amdgcn_mfma_f32_16x16x32_bf16(af, bf, g, 0, 0, 0);
      }
      const int gn = tn*16 + l16;          // C/D: n = lane&15, m = quad*4+r
      #pragma unroll
      for (int rr=0;rr<4;rr++){
        const int gm = tm*16 + quad*4 + rr;
        if (gm < F_SZ && gn < F_SZ && gn >= gm)
          gbuf[hw][gm*F_SZ - ((gm*(gm-1))>>1) + (gn-gm)] = f2b(g[rr]);
      }
    }
    __syncthreads();
    if (t < 160){
      #pragma unroll
      for (int hh=0; hh<2; hh++)
        *(uint4*)&Gp[(size_t)(r*2+hh)*KG + t*8] = *(const uint4*)&gbuf[hh][t*8];
    }
  } else if (r < 8704){
    const int d = r - 8192;
    #pragma unroll
    for (int i=0;i<4;i++){
      int k4 = (i*256+t)*4;
      if (k4 < KL){
        float4 v = *(const float4*)&Wl[(size_t)d*KL + k4];
        u16* o = &WlT[(size_t)d*KL + k4];
        o[0]=f2b(v.x); o[1]=f2b(v.y); o[2]=f2b(v.z); o[3]=f2b(v.w);
      }
    }
  } else if (r < 9216){
    const int d = r - 8704;
    const float* prow = &Pq[d*F_SZ];
    u16* orow = &pqq[(size_t)d*KG];
    int trif = 0;
    for (int f=0; f<F_SZ; f++){
      int len = F_SZ - f;
      if (t < len)
        orow[trif + t] = f2b(prow[f]*prow[f+t]*(t ? 2.f : 1.f));
      trif += len;
    }
    if (t < 5) orow[1275+t] = 0;
  } else if (r < 11264){
    int idx = (r-9216)*256 + t;          // 524288
    int k = idx & 511, n = idx >> 9;
    w0T[idx] = f2b(w0[(size_t)k*H1_SZ + n]);
  } else if (r < 13312){
    int idx = (r-11264)*256 + t;         // 524288
    int k = idx & 1023, n = idx >> 10;
    w1T[idx] = f2b(w1[(size_t)k*H2_SZ + n]);
  } else {
    int rr = r - 13312;
    int h = (rr & 3)*256 + t;
    int d0 = (rr >> 2)*64;
    float acc = (d0 == 0) ? b0[h] : 0.f;
    #pragma unroll 8
    for (int d=0; d<64; d++) acc += pb[d0+d]*w0[(size_t)(d0+d)*H1_SZ + h];
    atomicAdd(&cvec[h], acc);
  }
}

// BK=128 XOR-swizzled LDS tiles (r12 proven): rows are 256 B; LDS slot
// (row, block j in [0,16)) holds global block (j XOR (row&7)). Staged by
// lane fetching global block ((lane&15) XOR (row&7)) (4 rows/call);
// fragments read offset ((ks*4+quad) XOR (l16&7))*8.

// ---------------- fused product layer (r17 exact, FROZEN): 128m x 128n,
// 64 KB LDS, 2 blocks/CU, 512-block grid, 32x128 wave tiles.
__global__ __launch_bounds__(256, 2) void k_prod(
    const u16* __restrict__ Ae,    // embT (B, KL)
    const u16* __restrict__ Bw,    // WlT  (D, KL)
    const u16* __restrict__ Ag,    // Gp   (B, KG)
    const u16* __restrict__ Bq,    // pqq  (D, KG)
    const float* __restrict__ pbias,
    u16* __restrict__ y0)          // (B, D)
{
  __shared__ __align__(16) u16 As[128*128];   // 32 KB
  __shared__ __align__(16) u16 Bs[128*128];   // 32 KB
  const int tid  = threadIdx.x;
  const int wave = tid >> 6, lane = tid & 63;
  const int quad = lane >> 4, l16 = lane & 15;
  int bx, by;  swz(blockIdx.x, 2, bx, by);    // 512 blocks: 4 n-tiles, 128 m-tiles
  const int n0 = bx * 128, m0 = by * 128;
  const int lr4 = lane >> 4;
  const int cb  = lane & 15;
  const int sw  = (l16 & 7);

  f32x4v acc1[2][8], acc2[2][8];
  #pragma unroll
  for (int i=0;i<2;i++)
    #pragma unroll
    for (int j=0;j<8;j++){
      acc1[i][j] = (f32x4v){0.f,0.f,0.f,0.f};
      acc2[i][j] = (f32x4v){0.f,0.f,0.f,0.f};
    }

  auto run = [&](const u16* Ap, const u16* Bp, int K, f32x4v (&acc)[2][8]){
    for (int k0 = 0; k0 < K; k0 += 128){
      __syncthreads();
      #pragma unroll
      for (int c=0;c<8;c++){
        const int r0 = wave*32 + c*4;
        const int row = r0 + lr4;
        gload16(Ap + (size_t)(m0 + row)*K + k0 + ((cb ^ (row & 7)) << 3), As + r0*128);
      }
      #pragma unroll
      for (int c=0;c<8;c++){
        const int r0 = wave*32 + c*4;
        const int row = r0 + lr4;
        gload16(Bp + (size_t)(n0 + row)*K + k0 + ((cb ^ (row & 7)) << 3), Bs + r0*128);
      }
      __syncthreads();
      #pragma unroll
      for (int ks=0; ks<4; ks++){
        bf16x8v af[2], bfr[8];
        #pragma unroll
        for (int mt=0;mt<2;mt++)
          af[mt] = *(const bf16x8v*)&As[(wave*32+mt*16+l16)*128 + (((ks*4+quad) ^ sw))*8];
        #pragma unroll
        for (int nt=0;nt<8;nt++)
          bfr[nt] = *(const bf16x8v*)&Bs[(nt*16+l16)*128 + (((ks*4+quad) ^ sw))*8];
        #pragma unroll
        for (int mt=0;mt<2;mt++)
          #pragma unroll
          for (int nt=0;nt<8;nt++)
            acc[mt][nt] = __builtin_amdgcn_mfma_f32_16x16x32_bf16(af[mt], bfr[nt], acc[mt][nt], 0, 0, 0);
      }
    }
  };

  run(Ae, Bw, KL, acc1);     // lz
  run(Ag, Bq, KG, acc2);     // lp^2

  #pragma unroll
  for (int nt=0;nt<8;nt++){
    const int n = n0 + nt*16 + l16;
    const float bv = pbias[n];
    #pragma unroll
    for (int mt=0;mt<2;mt++){
      const int mb = m0 + wave*32 + mt*16 + quad*4;
      #pragma unroll
      for (int r=0;r<4;r++){
        float v = acc1[mt][nt][r] + sqrtf(fmaxf(acc2[mt][nt][r], 0.f)) + bv;
        v = (v > 0.f ? v : 0.f) - bv;
        y0[(size_t)(mb+r)*D_SZ + n] = f2b(v);
      }
    }
  }
}

// ---------------- BT GEMM v3 (r12 exact, FROZEN): BK=128, 64m x 128n,
// 48 KB LDS (3 blocks/CU). Stats over v = acc+bias[n]; store centered acc.
__global__ __launch_bounds__(256) void gemm_bt(
    const u16* __restrict__ A, const u16* __restrict__ Bm,
    u16* __restrict__ C, const float* __restrict__ bias,
    float* __restrict__ S1, float* __restrict__ S2,
    int nblog2, int N, int K)
{
  __shared__ __align__(16) u16 As[64*128];    // 16 KB
  __shared__ __align__(16) u16 Bs[128*128];   // 32 KB
  const int tid  = threadIdx.x;
  const int wave = tid >> 6, lane = tid & 63;
  const int quad = lane >> 4, l16 = lane & 15;
  int bx, by;  swz(blockIdx.x, nblog2, bx, by);
  const int n0 = bx * 128, m0 = by * 64;
  const int wr = wave >> 1, wc = wave & 1;
  const int lr4 = lane >> 4;
  const int cb  = lane & 15;
  const int sw  = (l16 & 7);

  f32x4v acc[2][4];
  #pragma unroll
  for (int i=0;i<2;i++)
    #pragma unroll
    for (int j=0;j<4;j++)
      acc[i][j] = (f32x4v){0.f,0.f,0.f,0.f};

  for (int k0 = 0; k0 < K; k0 += 128){
    __syncthreads();
    #pragma unroll
    for (int c=0;c<4;c++){
      const int r0 = wave*16 + c*4;
      const int row = r0 + lr4;
      gload16(A + (size_t)(m0 + row)*K + k0 + ((cb ^ (row & 7)) << 3), As + r0*128);
    }
    #pragma unroll
    for (int c=0;c<8;c++){
      const int r0 = wave*32 + c*4;
      const int row = r0 + lr4;
      gload16(Bm + (size_t)(n0 + row)*K + k0 + ((cb ^ (row & 7)) << 3), Bs + r0*128);
    }
    __syncthreads();
    #pragma unroll
    for (int ks=0; ks<4; ks++){
      bf16x8v af[2], bfr[4];
      #pragma unroll
      for (int mt=0;mt<2;mt++)
        af[mt] = *(const bf16x8v*)&As[(wr*32+mt*16+l16)*128 + (((ks*4+quad) ^ sw))*8];
      #pragma unroll
      for (int nt=0;nt<4;nt++)
        bfr[nt] = *(const bf16x8v*)&Bs[(wc*64+nt*16+l16)*128 + (((ks*4+quad) ^ sw))*8];
      #pragma unroll
      for (int mt=0;mt<2;mt++)
        #pragma unroll
        for (int nt=0;nt<4;nt++)
          acc[mt][nt] = __builtin_amdgcn_mfma_f32_16x16x32_bf16(af[mt], bfr[nt], acc[mt][nt], 0, 0, 0);
    }
  }

  // epilogue; C/D layout: n = lane&15, m = quad*4 + reg
  #pragma unroll
  for (int nt=0;nt<4;nt++){
    const int n = n0 + wc*64 + nt*16 + l16;
    const float bv = bias[n];
    float ls1 = 0.f, ls2 = 0.f;
    #pragma unroll
    for (int mt=0;mt<2;mt++){
      const int mb = m0 + wr*32 + mt*16 + quad*4;
      #pragma unroll
      for (int r=0;r<4;r++){
        float v = acc[mt][nt][r] + bv;
        C[(size_t)(mb+r)*N + n] = f2b(acc[mt][nt][r]);   // centered store
        ls1 += v; ls2 += v*v;
      }
    }
    ls1 += __shfl_xor(ls1, 16); ls2 += __shfl_xor(ls2, 16);
    ls1 += __shfl_xor(ls1, 32); ls2 += __shfl_xor(ls2, 32);
    if (quad == 0){ atomicAdd(&S1[n], ls1); atomicAdd(&S2[n], ls2); }
  }
}

// ---------------- BN finalize (r23, layer-0): per-column a, b for gemm_bn.
// Stored z1 is (z_full - cvec): b = bnof - m*a + a*cvec[n].
__global__ void k_bnfin(const float* __restrict__ S1, const float* __restrict__ S2,
                        const float* __restrict__ bnsc, const float* __restrict__ bnof,
                        const float* __restrict__ cadd,
                        float* __restrict__ Aout, float* __restrict__ Bout)
{
  int i = blockIdx.x*256 + threadIdx.x;
  const float invB = 1.f / 16384.f;
  float m   = S1[i]*invB;
  float var = S2[i]*invB - m*m;
  float a   = bnsc[0] * rsqrtf(var + 1e-10f);
  Aout[i] = a;
  Bout[i] = bnof[0] - m*a + a*cadd[i];
}

// ---------------- layer-1 GEMM, BN+relu fused via T14 split (r23, kept:
// 321.6 -> 319.4). Chunk t+1's A loads ISSUE right after the barrier (latency
// hides under chunk t's MFMA cluster); convert + swizzled ds_write at the top
// of t+1. Kills k_bnapply + the y1 HBM round-trip. Bit-identical y1 values.
__global__ __launch_bounds__(256) void gemm_bn(
    const u16* __restrict__ Z,     // z1c (B, 1024) centered bf16
    const u16* __restrict__ Bm,    // w1T (512, 1024)
    const float* __restrict__ Aa, const float* __restrict__ Bb,
    u16* __restrict__ C,           // z2c (B, 512) centered
    const float* __restrict__ bias,
    float* __restrict__ S1, float* __restrict__ S2)
{
  __shared__ __align__(16) u16 As[64*128];    // 16 KB
  __shared__ __align__(16) u16 Bs[128*128];   // 32 KB
  const int tid  = threadIdx.x;
  const int wave = tid >> 6, lane = tid & 63;
  const int quad = lane >> 4, l16 = lane & 15;
  int bx, by;  swz(blockIdx.x, 2, bx, by);    // 4 n-tiles, 256 m-tiles
  const int n0 = bx * 128, m0 = by * 64;
  const int wr = wave >> 1, wc = wave & 1;
  const int lr4 = lane >> 4;
  const int cb  = lane & 15;
  const int sw  = (l16 & 7);

  f32x4v acc[2][4];
  #pragma unroll
  for (int i=0;i<2;i++)
    #pragma unroll
    for (int j=0;j<4;j++)
      acc[i][j] = (f32x4v){0.f,0.f,0.f,0.f};

  uint4 zA[4];
  auto loadA = [&](int k0){
    #pragma unroll
    for (int c=0;c<4;c++){
      const int row = wave*16 + c*4 + lr4;
      const int col = k0 + ((cb ^ (row & 7)) << 3);
      zA[c] = *(const uint4*)&Z[(size_t)(m0 + row)*H1_SZ + col];
    }
  };

  loadA(0);                          // prologue: A-chunk 0 in flight
  for (int t = 0; t < 8; ++t){       // K = 1024, BK = 128
    const int k0 = t*128;
    __syncthreads();                 // LDS from chunk t-1 fully consumed
    // convert + write A (data arrived during previous MFMA phase)
    #pragma unroll
    for (int c=0;c<4;c++){
      const int row = wave*16 + c*4 + lr4;
      const int col = k0 + ((cb ^ (row & 7)) << 3);
      float4 a0 = *(const float4*)&Aa[col];
      float4 a1 = *(const float4*)&Aa[col+4];
      float4 b0 = *(const float4*)&Bb[col];
      float4 b1 = *(const float4*)&Bb[col+4];
      float av[8] = {a0.x,a0.y,a0.z,a0.w,a1.x,a1.y,a1.z,a1.w};
      float bv[8] = {b0.x,b0.y,b0.z,b0.w,b1.x,b1.y,b1.z,b1.w};
      union { uint4 q; u16 s[8]; } z, o;
      z.q = zA[c];
      #pragma unroll
      for (int j=0;j<8;j++){
        float v = b2f(z.s[j]) * av[j] + bv[j];
        o.s[j] = f2b(v > 0.f ? v : 0.f);
      }
      *(uint4*)&As[row*128 + cb*8] = o.q;   // ds_write_b128, swizzled slot
    }
    #pragma unroll
    for (int c=0;c<8;c++){
      const int r0 = wave*32 + c*4;
      const int row = r0 + lr4;
      gload16(Bm + (size_t)(n0 + row)*H1_SZ + k0 + ((cb ^ (row & 7)) << 3), Bs + r0*128);
    }
    __syncthreads();                 // Bs ready, As written
    if (t < 7) loadA(k0 + 128);      // ISSUE EARLY: latency hides under MFMA
    #pragma unroll
    for (int ks=0; ks<4; ks++){
      bf16x8v af[2], bfr[4];
      #pragma unroll
      for (int mt=0;mt<2;mt++)
        af[mt] = *(const bf16x8v*)&As[(wr*32+mt*16+l16)*128 + (((ks*4+quad) ^ sw))*8];
      #pragma unroll
      for (int nt=0;nt<4;nt++)
        bfr[nt] = *(const bf16x8v*)&Bs[(wc*64+nt*16+l16)*128 + (((ks*4+quad) ^ sw))*8];
      #pragma unroll
      for (int mt=0;mt<2;mt++)
        #pragma unroll
        for (int nt=0;nt<4;nt++)
          acc[mt][nt] = __builtin_amdgcn_mfma_f32_16x16x32_bf16(af[mt], bfr[nt], acc[mt][nt], 0, 0, 0);
    }
  }

  // epilogue: store centered acc, stats over acc+b1 (== gemm_bt)
  #pragma unroll
  for (int nt=0;nt<4;nt++){
    const int n = n0 + wc*64 + nt*16 + l16;
    const float bv = bias[n];
    float ls1 = 0.f, ls2 = 0.f;
    #pragma unroll
    for (int mt=0;mt<2;mt++){
      const int mb = m0 + wr*32 + mt*16 + quad*4;
      #pragma unroll
      for (int r=0;r<4;r++){
        float v = acc[mt][nt][r] + bv;
        C[(size_t)(mb+r)*H2_SZ + n] = f2b(acc[mt][nt][r]);
        ls1 += v; ls2 += v*v;
      }
    }
    ls1 += __shfl_xor(ls1, 16); ls2 += __shfl_xor(ls2, 16);
    ls1 += __shfl_xor(ls1, 32); ls2 += __shfl_xor(ls2, 32);
    if (quad == 0){ atomicAdd(&S1[n], ls1); atomicAdd(&S2[n], ls2); }
  }
}

// ---------------- final: inlined BN finalize + relu + dot + sigmoid (r17).
__global__ __launch_bounds__(256) void k_out(
    const u16* __restrict__ Z2, const float* __restrict__ wvec,
    const float* __restrict__ obp,
    const float* __restrict__ S1, const float* __restrict__ S2,
    const float* __restrict__ bnsc, const float* __restrict__ bnof,
    const float* __restrict__ cadd,
    float* __restrict__ out)
{
  const int wave = threadIdx.x >> 6, lane = threadIdx.x & 63;
  const int b = blockIdx.x*4 + wave;
  const int n0 = lane*8;
  const float invB = 1.f / 16384.f;
  const float sc = bnsc[0], of = bnof[0];
  union { uint4 q; u16 s[8]; } z;
  z.q = *(const uint4*)&Z2[(size_t)b*H2_SZ + n0];
  float4 wa = *(const float4*)&wvec[n0];
  float4 wb = *(const float4*)&wvec[n0+4];
  float wv[8] = {wa.x,wa.y,wa.z,wa.w,wb.x,wb.y,wb.z,wb.w};
  float s = 0.f;
  #pragma unroll
  for (int j=0;j<8;j++){
    int n = n0 + j;
    float m   = S1[n]*invB;
    float var = S2[n]*invB - m*m;
    float a   = sc * rsqrtf(var + 1e-10f);
    float bb  = of - m*a + a*cadd[n];
    float y = b2f(z.s[j]) * a + bb;
    y = y > 0.f ? y : 0.f;
    s += y * wv[j];
  }
  s += __shfl_xor(s,1);  s += __shfl_xor(s,2);  s += __shfl_xor(s,4);
  s += __shfl_xor(s,8);  s += __shfl_xor(s,16); s += __shfl_xor(s,32);
  if (lane == 0){
    float x = s + obp[0];
    out[b] = 1.f / (1.f + expf(-x));
  }
}

// ---------------- workspace map (bytes) ----------------
// embT @ 0          : 104857600  (B x 3200 bf16; dead after k_prod; reused:)
//   z1c @ 0         :  33554432  (bf16 centered pre-BN layer0)
//   z2c @ 100663296 :  16777216  (bf16 centered pre-BN layer1)
// Gp   @ 104857600  :  41943040  (B x 1280 bf16; dead after k_prod)
// WlT  @ 146800640  :   3276800
// pqq  @ 150077440  :   1310720
// y0   @ 151388160  :  16777216  (bf16, bias-centered)
// W0T  @ 168165376  :   1048576
// W1T  @ 169213952  :   1048576
// stats@ 170262528  : 16 KB ZEROED: S1a[1024] S2a[1024] S1b[512] S2b[512] cvec[1024]
//      then A0[1024] B0[1024] (fp32, k_bnfin output)
// total ~ 170.3 MB

extern "C" void kernel_launch(void* const* d_in, const int* in_sizes, int n_in,
                              void* d_out, int out_size, void* d_ws, size_t ws_size,
                              hipStream_t stream)
{
  const int*   fidx  = (const int*)d_in[0];
  const float* fval  = (const float*)d_in[1];
  const float* femb  = (const float*)d_in[2];
  const float* wl    = (const float*)d_in[3];
  const float* pbias = (const float*)d_in[4];
  const float* pq    = (const float*)d_in[5];
  const float* w0    = (const float*)d_in[6];
  const float* b0    = (const float*)d_in[7];
  const float* w1    = (const float*)d_in[8];
  const float* b1    = (const float*)d_in[9];
  const float* bnsc  = (const float*)d_in[10];
  const float* bnof  = (const float*)d_in[11];
  const float* ow    = (const float*)d_in[12];
  const float* ob    = (const float*)d_in[13];
  float* out = (float*)d_out;

  char* ws = (char*)d_ws;
  u16*   embT = (u16*)(ws + 0);
  u16*   z1b  = (u16*)(ws + 0);
  u16*   z2b  = (u16*)(ws + 100663296);
  u16*   gpb  = (u16*)(ws + 104857600);
  u16*   wlT  = (u16*)(ws + 146800640);
  u16*   pqqb = (u16*)(ws + 150077440);
  u16*   y0b  = (u16*)(ws + 151388160);
  u16*   w0T  = (u16*)(ws + 168165376);
  u16*   w1T  = (u16*)(ws + 169213952);
  float* S1a  = (float*)(ws + 170262528);
  float* S2a  = S1a + 1024;
  float* S1b  = S2a + 1024;
  float* S2b  = S1b + 512;
  float* cvec = S2b + 512;
  float* A0   = cvec + 1024;
  float* B0   = A0 + 1024;

  hipMemsetAsync((void*)S1a, 0, 16384, stream);      // S1a,S2a,S1b,S2b,cvec

  k_front<<<13344, 256, 0, stream>>>(fidx, fval, femb, embT, gpb,
                                     wl, wlT, pq, pqqb, w0, w0T, w1, w1T,
                                     pbias, b0, cvec);

  k_prod<<<512, 256, 0, stream>>>(embT, wlT, gpb, pqqb, pbias, y0b);

  // layer 0: z1c (centered bf16) + batch stats
  gemm_bt<<<2048, 256, 0, stream>>>(y0b, w0T, z1b, cvec, S1a, S2a,
                                    3, H1_SZ, D_SZ);
  k_bnfin<<<4, 256, 0, stream>>>(S1a, S2a, bnsc, bnof, cvec, A0, B0);

  // layer 1: BN(z1c)+relu fused into A-staging (T14 split); z2c + stats
  gemm_bn<<<1024, 256, 0, stream>>>(z1b, w1T, A0, B0, z2b, b1, S1b, S2b);

  k_out<<<4096, 256, 0, stream>>>(z2b, ow, ob, S1b, S2b, bnsc, bnof, b1, out);
}

// Round 18
// 314.508 us; speedup vs baseline: 1.0589x; 1.0075x over previous
//
#include <hip/hip_runtime.h>

typedef unsigned short u16;
typedef __attribute__((ext_vector_type(8))) short bf16x8v;
typedef __attribute__((ext_vector_type(4))) float f32x4v;

#define B_SZ 16384
#define F_SZ 50
#define E_SZ 64
#define D_SZ 512
#define H1_SZ 1024
#define H2_SZ 512
#define KL 3200   // lz K: k = f*64+e, f<50 -- NO padding (f-major)
#define KG 1280   // gram K: packed upper-tri 1275 -> padded 1280

__device__ __forceinline__ float b2f(u16 u){
  union { unsigned int i; float f; } v; v.i = ((unsigned int)u) << 16; return v.f;
}
__device__ __forceinline__ u16 f2b(float f){
  union { float f; unsigned int i; } v; v.f = f;
  unsigned int r = v.i + 0x7FFFu + ((v.i >> 16) & 1u);
  return (u16)(r >> 16);
}

// async global->LDS, 16B/lane. g is per-lane (base + lane*16B); lds base is
// wave-uniform; HW writes lds_base + lane*16.
__device__ __forceinline__ void gload16(const u16* g, u16* lds_base_uniform){
#if __has_builtin(__builtin_amdgcn_global_load_lds)
  __builtin_amdgcn_global_load_lds(
      (const __attribute__((address_space(1))) unsigned int*)g,
      (__attribute__((address_space(3))) unsigned int*)lds_base_uniform,
      16, 0, 0);
#else
  int lane = threadIdx.x & 63;
  *(uint4*)(lds_base_uniform + lane*8) = *(const uint4*)g;
#endif
}

// XCD-aware grid swizzle (r11: verified FETCH 270->99 MB): blocks sharing an
// A(m)-tile get IDs equal mod 8 -> same XCD L2. x = n-tile, y = m-tile.
__device__ __forceinline__ void swz(int id, int nblog2, int &x, int &y){
  int xcd = id & 7, j = id >> 3;
  x = j & ((1 << nblog2) - 1);
  y = ((j >> nblog2) << 3) | xcd;
}

// ---------------- front kernel v3 (r25): gather + Gram + weight prep.
// r25: gather loads are BATCH-ISSUED (all 7 float4 gathers into registers
// before any convert/store -- 7 outstanding VMEM/thread instead of ~1-2;
// VGPR was 16, headroom is huge). Same T14 issue-early principle that fixed
// gemm_bn. Semantics bit-identical to r20/r24. Ranges:
//   [0,8192)       gather/Gram for b = 2r, 2r+1
//   [8192,8704)    WlT  = bf16(product_linear)
//   [8704,9216)    pqq[d, packed(f,f')] = pq_f*pq_f'*(f==f'?1:2), pad 0
//   [9216,11264)   w0T (N,K) bf16
//   [11264,13312)  w1T (N,K) bf16
//   [13312,13344)  cvec = b0 + pbias @ w0
__global__ __launch_bounds__(256) void k_front(
    const int* __restrict__ fidx, const float* __restrict__ fval,
    const float* __restrict__ femb, u16* __restrict__ embT,
    u16* __restrict__ Gp,
    const float* __restrict__ Wl, u16* __restrict__ WlT,
    const float* __restrict__ Pq, u16* __restrict__ pqq,
    const float* __restrict__ w0, u16* __restrict__ w0T,
    const float* __restrict__ w1, u16* __restrict__ w1T,
    const float* __restrict__ pb, const float* __restrict__ b0,
    float* __restrict__ cvec)
{
  __shared__ int   sidx[2][F_SZ];
  __shared__ float sfv[2][F_SZ];
  __shared__ __align__(16) u16 tile[2][64*72];   // rows 50..63 garbage, masked
  __shared__ __align__(16) u16 gbuf[2][KG];
  const int r = blockIdx.x, t = threadIdx.x;
  if (r < 8192){
    const int h  = t >> 7;
    const int th = t & 127;
    const int b  = r*2 + h;
    if (th < F_SZ){ sidx[h][th] = fidx[b*F_SZ+th]; sfv[h][th] = fval[b*F_SZ+th]; }
    if (th < 5) gbuf[h][1275+th] = 0;      // zero pad (NaN*0 hazard in MFMA)
    __syncthreads();
    // phase 1: ISSUE all gathers (7 outstanding VMEM/thread)
    float4 vv[7]; float ss[7];
    #pragma unroll
    for (int i=0;i<7;i++){
      int k4 = (i*128+th)*4;               // 4 consecutive e, same f
      if (k4 < F_SZ*E_SZ){
        int f = k4>>6, e = k4&63;
        vv[i] = *(const float4*)&femb[(size_t)sidx[h][f]*E_SZ + e];
        ss[i] = sfv[h][f];
      }
    }
    // phase 2: convert + store (tile for Gram, direct 8 B embT store)
    u16* orow = embT + (size_t)b*KL;
    #pragma unroll
    for (int i=0;i<7;i++){
      int k4 = (i*128+th)*4;
      if (k4 < F_SZ*E_SZ){
        int f = k4>>6, e = k4&63;
        float s = ss[i];
        u16 q0=f2b(vv[i].x*s), q1=f2b(vv[i].y*s), q2=f2b(vv[i].z*s), q3=f2b(vv[i].w*s);
        tile[h][f*72+e+0]=q0; tile[h][f*72+e+1]=q1;
        tile[h][f*72+e+2]=q2; tile[h][f*72+e+3]=q3;
        union { unsigned long long d; u16 s4[4]; } o4;
        o4.s4[0]=q0; o4.s4[1]=q1; o4.s4[2]=q2; o4.s4[3]=q3;
        *(unsigned long long*)&orow[k4] = o4.d;
      }
    }
    __syncthreads();
    // Gram -> gbuf packed upper-tri: idx(m,n) = 50m - m(m-1)/2 + (n-m), n>=m
    const int wave = t >> 6, lane = t & 63, quad = lane >> 4, l16 = lane & 15;
    const int hw = wave >> 1, lw = wave & 1;
    static const int TM[10] = {0,0,0,0,1,1,1,2,2,3};
    static const int TN[10] = {0,1,2,3,1,2,3,2,3,3};
    for (int ti = lw; ti < 10; ti += 2){
      const int tm = TM[ti], tn = TN[ti];
      f32x4v g = {0.f,0.f,0.f,0.f};
      #pragma unroll
      for (int ks=0;ks<2;ks++){
        bf16x8v af = *(const bf16x8v*)&tile[hw][(tm*16+l16)*72 + (ks*4+quad)*8];
        bf16x8v bf = *(const bf16x8v*)&tile[hw][(tn*16+l16)*72 + (ks*4+quad)*8];
        g = __builtin_amdgcn_mfma_f32_16x16x32_bf16(af, bf, g, 0, 0, 0);
      }
      const int gn = tn*16 + l16;          // C/D: n = lane&15, m = quad*4+r
      #pragma unroll
      for (int rr=0;rr<4;rr++){
        const int gm = tm*16 + quad*4 + rr;
        if (gm < F_SZ && gn < F_SZ && gn >= gm)
          gbuf[hw][gm*F_SZ - ((gm*(gm-1))>>1) + (gn-gm)] = f2b(g[rr]);
      }
    }
    __syncthreads();
    if (t < 160){
      #pragma unroll
      for (int hh=0; hh<2; hh++)
        *(uint4*)&Gp[(size_t)(r*2+hh)*KG + t*8] = *(const uint4*)&gbuf[hh][t*8];
    }
  } else if (r < 8704){
    const int d = r - 8192;
    #pragma unroll
    for (int i=0;i<4;i++){
      int k4 = (i*256+t)*4;
      if (k4 < KL){
        float4 v = *(const float4*)&Wl[(size_t)d*KL + k4];
        u16* o = &WlT[(size_t)d*KL + k4];
        o[0]=f2b(v.x); o[1]=f2b(v.y); o[2]=f2b(v.z); o[3]=f2b(v.w);
      }
    }
  } else if (r < 9216){
    const int d = r - 8704;
    const float* prow = &Pq[d*F_SZ];
    u16* orow = &pqq[(size_t)d*KG];
    int trif = 0;
    for (int f=0; f<F_SZ; f++){
      int len = F_SZ - f;
      if (t < len)
        orow[trif + t] = f2b(prow[f]*prow[f+t]*(t ? 2.f : 1.f));
      trif += len;
    }
    if (t < 5) orow[1275+t] = 0;
  } else if (r < 11264){
    int idx = (r-9216)*256 + t;          // 524288
    int k = idx & 511, n = idx >> 9;
    w0T[idx] = f2b(w0[(size_t)k*H1_SZ + n]);
  } else if (r < 13312){
    int idx = (r-11264)*256 + t;         // 524288
    int k = idx & 1023, n = idx >> 10;
    w1T[idx] = f2b(w1[(size_t)k*H2_SZ + n]);
  } else {
    int rr = r - 13312;
    int h = (rr & 3)*256 + t;
    int d0 = (rr >> 2)*64;
    float acc = (d0 == 0) ? b0[h] : 0.f;
    #pragma unroll 8
    for (int d=0; d<64; d++) acc += pb[d0+d]*w0[(size_t)(d0+d)*H1_SZ + h];
    atomicAdd(&cvec[h], acc);
  }
}

// BK=128 XOR-swizzled LDS tiles (r12 proven): rows are 256 B; LDS slot
// (row, block j in [0,16)) holds global block (j XOR (row&7)). Staged by
// lane fetching global block ((lane&15) XOR (row&7)) (4 rows/call);
// fragments read offset ((ks*4+quad) XOR (l16&7))*8.

// ---------------- fused product layer (r17 exact, FROZEN): 128m x 128n,
// 64 KB LDS, 2 blocks/CU, 512-block grid, 32x128 wave tiles.
__global__ __launch_bounds__(256, 2) void k_prod(
    const u16* __restrict__ Ae,    // embT (B, KL)
    const u16* __restrict__ Bw,    // WlT  (D, KL)
    const u16* __restrict__ Ag,    // Gp   (B, KG)
    const u16* __restrict__ Bq,    // pqq  (D, KG)
    const float* __restrict__ pbias,
    u16* __restrict__ y0)          // (B, D)
{
  __shared__ __align__(16) u16 As[128*128];   // 32 KB
  __shared__ __align__(16) u16 Bs[128*128];   // 32 KB
  const int tid  = threadIdx.x;
  const int wave = tid >> 6, lane = tid & 63;
  const int quad = lane >> 4, l16 = lane & 15;
  int bx, by;  swz(blockIdx.x, 2, bx, by);    // 512 blocks: 4 n-tiles, 128 m-tiles
  const int n0 = bx * 128, m0 = by * 128;
  const int lr4 = lane >> 4;
  const int cb  = lane & 15;
  const int sw  = (l16 & 7);

  f32x4v acc1[2][8], acc2[2][8];
  #pragma unroll
  for (int i=0;i<2;i++)
    #pragma unroll
    for (int j=0;j<8;j++){
      acc1[i][j] = (f32x4v){0.f,0.f,0.f,0.f};
      acc2[i][j] = (f32x4v){0.f,0.f,0.f,0.f};
    }

  auto run = [&](const u16* Ap, const u16* Bp, int K, f32x4v (&acc)[2][8]){
    for (int k0 = 0; k0 < K; k0 += 128){
      __syncthreads();
      #pragma unroll
      for (int c=0;c<8;c++){
        const int r0 = wave*32 + c*4;
        const int row = r0 + lr4;
        gload16(Ap + (size_t)(m0 + row)*K + k0 + ((cb ^ (row & 7)) << 3), As + r0*128);
      }
      #pragma unroll
      for (int c=0;c<8;c++){
        const int r0 = wave*32 + c*4;
        const int row = r0 + lr4;
        gload16(Bp + (size_t)(n0 + row)*K + k0 + ((cb ^ (row & 7)) << 3), Bs + r0*128);
      }
      __syncthreads();
      #pragma unroll
      for (int ks=0; ks<4; ks++){
        bf16x8v af[2], bfr[8];
        #pragma unroll
        for (int mt=0;mt<2;mt++)
          af[mt] = *(const bf16x8v*)&As[(wave*32+mt*16+l16)*128 + (((ks*4+quad) ^ sw))*8];
        #pragma unroll
        for (int nt=0;nt<8;nt++)
          bfr[nt] = *(const bf16x8v*)&Bs[(nt*16+l16)*128 + (((ks*4+quad) ^ sw))*8];
        #pragma unroll
        for (int mt=0;mt<2;mt++)
          #pragma unroll
          for (int nt=0;nt<8;nt++)
            acc[mt][nt] = __builtin_amdgcn_mfma_f32_16x16x32_bf16(af[mt], bfr[nt], acc[mt][nt], 0, 0, 0);
      }
    }
  };

  run(Ae, Bw, KL, acc1);     // lz
  run(Ag, Bq, KG, acc2);     // lp^2

  #pragma unroll
  for (int nt=0;nt<8;nt++){
    const int n = n0 + nt*16 + l16;
    const float bv = pbias[n];
    #pragma unroll
    for (int mt=0;mt<2;mt++){
      const int mb = m0 + wave*32 + mt*16 + quad*4;
      #pragma unroll
      for (int r=0;r<4;r++){
        float v = acc1[mt][nt][r] + sqrtf(fmaxf(acc2[mt][nt][r], 0.f)) + bv;
        v = (v > 0.f ? v : 0.f) - bv;
        y0[(size_t)(mb+r)*D_SZ + n] = f2b(v);
      }
    }
  }
}

// ---------------- BT GEMM v3 (r12 exact, FROZEN): BK=128, 64m x 128n,
// 48 KB LDS (3 blocks/CU). Stats over v = acc+bias[n]; store centered acc.
__global__ __launch_bounds__(256) void gemm_bt(
    const u16* __restrict__ A, const u16* __restrict__ Bm,
    u16* __restrict__ C, const float* __restrict__ bias,
    float* __restrict__ S1, float* __restrict__ S2,
    int nblog2, int N, int K)
{
  __shared__ __align__(16) u16 As[64*128];    // 16 KB
  __shared__ __align__(16) u16 Bs[128*128];   // 32 KB
  const int tid  = threadIdx.x;
  const int wave = tid >> 6, lane = tid & 63;
  const int quad = lane >> 4, l16 = lane & 15;
  int bx, by;  swz(blockIdx.x, nblog2, bx, by);
  const int n0 = bx * 128, m0 = by * 64;
  const int wr = wave >> 1, wc = wave & 1;
  const int lr4 = lane >> 4;
  const int cb  = lane & 15;
  const int sw  = (l16 & 7);

  f32x4v acc[2][4];
  #pragma unroll
  for (int i=0;i<2;i++)
    #pragma unroll
    for (int j=0;j<4;j++)
      acc[i][j] = (f32x4v){0.f,0.f,0.f,0.f};

  for (int k0 = 0; k0 < K; k0 += 128){
    __syncthreads();
    #pragma unroll
    for (int c=0;c<4;c++){
      const int r0 = wave*16 + c*4;
      const int row = r0 + lr4;
      gload16(A + (size_t)(m0 + row)*K + k0 + ((cb ^ (row & 7)) << 3), As + r0*128);
    }
    #pragma unroll
    for (int c=0;c<8;c++){
      const int r0 = wave*32 + c*4;
      const int row = r0 + lr4;
      gload16(Bm + (size_t)(n0 + row)*K + k0 + ((cb ^ (row & 7)) << 3), Bs + r0*128);
    }
    __syncthreads();
    #pragma unroll
    for (int ks=0; ks<4; ks++){
      bf16x8v af[2], bfr[4];
      #pragma unroll
      for (int mt=0;mt<2;mt++)
        af[mt] = *(const bf16x8v*)&As[(wr*32+mt*16+l16)*128 + (((ks*4+quad) ^ sw))*8];
      #pragma unroll
      for (int nt=0;nt<4;nt++)
        bfr[nt] = *(const bf16x8v*)&Bs[(wc*64+nt*16+l16)*128 + (((ks*4+quad) ^ sw))*8];
      #pragma unroll
      for (int mt=0;mt<2;mt++)
        #pragma unroll
        for (int nt=0;nt<4;nt++)
          acc[mt][nt] = __builtin_amdgcn_mfma_f32_16x16x32_bf16(af[mt], bfr[nt], acc[mt][nt], 0, 0, 0);
    }
  }

  // epilogue; C/D layout: n = lane&15, m = quad*4 + reg
  #pragma unroll
  for (int nt=0;nt<4;nt++){
    const int n = n0 + wc*64 + nt*16 + l16;
    const float bv = bias[n];
    float ls1 = 0.f, ls2 = 0.f;
    #pragma unroll
    for (int mt=0;mt<2;mt++){
      const int mb = m0 + wr*32 + mt*16 + quad*4;
      #pragma unroll
      for (int r=0;r<4;r++){
        float v = acc[mt][nt][r] + bv;
        C[(size_t)(mb+r)*N + n] = f2b(acc[mt][nt][r]);   // centered store
        ls1 += v; ls2 += v*v;
      }
    }
    ls1 += __shfl_xor(ls1, 16); ls2 += __shfl_xor(ls2, 16);
    ls1 += __shfl_xor(ls1, 32); ls2 += __shfl_xor(ls2, 32);
    if (quad == 0){ atomicAdd(&S1[n], ls1); atomicAdd(&S2[n], ls2); }
  }
}

// ---------------- BN finalize (r23, layer-0): per-column a, b for gemm_bn.
// Stored z1 is (z_full - cvec): b = bnof - m*a + a*cvec[n].
__global__ void k_bnfin(const float* __restrict__ S1, const float* __restrict__ S2,
                        const float* __restrict__ bnsc, const float* __restrict__ bnof,
                        const float* __restrict__ cadd,
                        float* __restrict__ Aout, float* __restrict__ Bout)
{
  int i = blockIdx.x*256 + threadIdx.x;
  const float invB = 1.f / 16384.f;
  float m   = S1[i]*invB;
  float var = S2[i]*invB - m*m;
  float a   = bnsc[0] * rsqrtf(var + 1e-10f);
  Aout[i] = a;
  Bout[i] = bnof[0] - m*a + a*cadd[i];
}

// ---------------- layer-1 GEMM, BN+relu fused via T14 split (r23, kept:
// 321.6 -> 319.4 -> 316.9). Chunk t+1's A loads ISSUE right after the
// barrier (latency hides under chunk t's MFMA cluster); convert + swizzled
// ds_write at the top of t+1. Kills k_bnapply + the y1 HBM round-trip.
__global__ __launch_bounds__(256) void gemm_bn(
    const u16* __restrict__ Z,     // z1c (B, 1024) centered bf16
    const u16* __restrict__ Bm,    // w1T (512, 1024)
    const float* __restrict__ Aa, const float* __restrict__ Bb,
    u16* __restrict__ C,           // z2c (B, 512) centered
    const float* __restrict__ bias,
    float* __restrict__ S1, float* __restrict__ S2)
{
  __shared__ __align__(16) u16 As[64*128];    // 16 KB
  __shared__ __align__(16) u16 Bs[128*128];   // 32 KB
  const int tid  = threadIdx.x;
  const int wave = tid >> 6, lane = tid & 63;
  const int quad = lane >> 4, l16 = lane & 15;
  int bx, by;  swz(blockIdx.x, 2, bx, by);    // 4 n-tiles, 256 m-tiles
  const int n0 = bx * 128, m0 = by * 64;
  const int wr = wave >> 1, wc = wave & 1;
  const int lr4 = lane >> 4;
  const int cb  = lane & 15;
  const int sw  = (l16 & 7);

  f32x4v acc[2][4];
  #pragma unroll
  for (int i=0;i<2;i++)
    #pragma unroll
    for (int j=0;j<4;j++)
      acc[i][j] = (f32x4v){0.f,0.f,0.f,0.f};

  uint4 zA[4];
  auto loadA = [&](int k0){
    #pragma unroll
    for (int c=0;c<4;c++){
      const int row = wave*16 + c*4 + lr4;
      const int col = k0 + ((cb ^ (row & 7)) << 3);
      zA[c] = *(const uint4*)&Z[(size_t)(m0 + row)*H1_SZ + col];
    }
  };

  loadA(0);                          // prologue: A-chunk 0 in flight
  for (int t = 0; t < 8; ++t){       // K = 1024, BK = 128
    const int k0 = t*128;
    __syncthreads();                 // LDS from chunk t-1 fully consumed
    // convert + write A (data arrived during previous MFMA phase)
    #pragma unroll
    for (int c=0;c<4;c++){
      const int row = wave*16 + c*4 + lr4;
      const int col = k0 + ((cb ^ (row & 7)) << 3);
      float4 a0 = *(const float4*)&Aa[col];
      float4 a1 = *(const float4*)&Aa[col+4];
      float4 b0 = *(const float4*)&Bb[col];
      float4 b1 = *(const float4*)&Bb[col+4];
      float av[8] = {a0.x,a0.y,a0.z,a0.w,a1.x,a1.y,a1.z,a1.w};
      float bv[8] = {b0.x,b0.y,b0.z,b0.w,b1.x,b1.y,b1.z,b1.w};
      union { uint4 q; u16 s[8]; } z, o;
      z.q = zA[c];
      #pragma unroll
      for (int j=0;j<8;j++){
        float v = b2f(z.s[j]) * av[j] + bv[j];
        o.s[j] = f2b(v > 0.f ? v : 0.f);
      }
      *(uint4*)&As[row*128 + cb*8] = o.q;   // ds_write_b128, swizzled slot
    }
    #pragma unroll
    for (int c=0;c<8;c++){
      const int r0 = wave*32 + c*4;
      const int row = r0 + lr4;
      gload16(Bm + (size_t)(n0 + row)*H1_SZ + k0 + ((cb ^ (row & 7)) << 3), Bs + r0*128);
    }
    __syncthreads();                 // Bs ready, As written
    if (t < 7) loadA(k0 + 128);      // ISSUE EARLY: latency hides under MFMA
    #pragma unroll
    for (int ks=0; ks<4; ks++){
      bf16x8v af[2], bfr[4];
      #pragma unroll
      for (int mt=0;mt<2;mt++)
        af[mt] = *(const bf16x8v*)&As[(wr*32+mt*16+l16)*128 + (((ks*4+quad) ^ sw))*8];
      #pragma unroll
      for (int nt=0;nt<4;nt++)
        bfr[nt] = *(const bf16x8v*)&Bs[(wc*64+nt*16+l16)*128 + (((ks*4+quad) ^ sw))*8];
      #pragma unroll
      for (int mt=0;mt<2;mt++)
        #pragma unroll
        for (int nt=0;nt<4;nt++)
          acc[mt][nt] = __builtin_amdgcn_mfma_f32_16x16x32_bf16(af[mt], bfr[nt], acc[mt][nt], 0, 0, 0);
    }
  }

  // epilogue: store centered acc, stats over acc+b1 (== gemm_bt)
  #pragma unroll
  for (int nt=0;nt<4;nt++){
    const int n = n0 + wc*64 + nt*16 + l16;
    const float bv = bias[n];
    float ls1 = 0.f, ls2 = 0.f;
    #pragma unroll
    for (int mt=0;mt<2;mt++){
      const int mb = m0 + wr*32 + mt*16 + quad*4;
      #pragma unroll
      for (int r=0;r<4;r++){
        float v = acc[mt][nt][r] + bv;
        C[(size_t)(mb+r)*H2_SZ + n] = f2b(acc[mt][nt][r]);
        ls1 += v; ls2 += v*v;
      }
    }
    ls1 += __shfl_xor(ls1, 16); ls2 += __shfl_xor(ls2, 16);
    ls1 += __shfl_xor(ls1, 32); ls2 += __shfl_xor(ls2, 32);
    if (quad == 0){ atomicAdd(&S1[n], ls1); atomicAdd(&S2[n], ls2); }
  }
}

// ---------------- final: inlined BN finalize + relu + dot + sigmoid (r17).
__global__ __launch_bounds__(256) void k_out(
    const u16* __restrict__ Z2, const float* __restrict__ wvec,
    const float* __restrict__ obp,
    const float* __restrict__ S1, const float* __restrict__ S2,
    const float* __restrict__ bnsc, const float* __restrict__ bnof,
    const float* __restrict__ cadd,
    float* __restrict__ out)
{
  const int wave = threadIdx.x >> 6, lane = threadIdx.x & 63;
  const int b = blockIdx.x*4 + wave;
  const int n0 = lane*8;
  const float invB = 1.f / 16384.f;
  const float sc = bnsc[0], of = bnof[0];
  union { uint4 q; u16 s[8]; } z;
  z.q = *(const uint4*)&Z2[(size_t)b*H2_SZ + n0];
  float4 wa = *(const float4*)&wvec[n0];
  float4 wb = *(const float4*)&wvec[n0+4];
  float wv[8] = {wa.x,wa.y,wa.z,wa.w,wb.x,wb.y,wb.z,wb.w};
  float s = 0.f;
  #pragma unroll
  for (int j=0;j<8;j++){
    int n = n0 + j;
    float m   = S1[n]*invB;
    float var = S2[n]*invB - m*m;
    float a   = sc * rsqrtf(var + 1e-10f);
    float bb  = of - m*a + a*cadd[n];
    float y = b2f(z.s[j]) * a + bb;
    y = y > 0.f ? y : 0.f;
    s += y * wv[j];
  }
  s += __shfl_xor(s,1);  s += __shfl_xor(s,2);  s += __shfl_xor(s,4);
  s += __shfl_xor(s,8);  s += __shfl_xor(s,16); s += __shfl_xor(s,32);
  if (lane == 0){
    float x = s + obp[0];
    out[b] = 1.f / (1.f + expf(-x));
  }
}

// ---------------- workspace map (bytes) ----------------
// embT @ 0          : 104857600  (B x 3200 bf16; dead after k_prod; reused:)
//   z1c @ 0         :  33554432  (bf16 centered pre-BN layer0)
//   z2c @ 100663296 :  16777216  (bf16 centered pre-BN layer1)
// Gp   @ 104857600  :  41943040  (B x 1280 bf16; dead after k_prod)
// WlT  @ 146800640  :   3276800
// pqq  @ 150077440  :   1310720
// y0   @ 151388160  :  16777216  (bf16, bias-centered)
// W0T  @ 168165376  :   1048576
// W1T  @ 169213952  :   1048576
// stats@ 170262528  : 16 KB ZEROED: S1a[1024] S2a[1024] S1b[512] S2b[512] cvec[1024]
//      then A0[1024] B0[1024] (fp32, k_bnfin output)
// total ~ 170.3 MB

extern "C" void kernel_launch(void* const* d_in, const int* in_sizes, int n_in,
                              void* d_out, int out_size, void* d_ws, size_t ws_size,
                              hipStream_t stream)
{
  const int*   fidx  = (const int*)d_in[0];
  const float* fval  = (const float*)d_in[1];
  const float* femb  = (const float*)d_in[2];
  const float* wl    = (const float*)d_in[3];
  const float* pbias = (const float*)d_in[4];
  const float* pq    = (const float*)d_in[5];
  const float* w0    = (const float*)d_in[6];
  const float* b0    = (const float*)d_in[7];
  const float* w1    = (const float*)d_in[8];
  const float* b1    = (const float*)d_in[9];
  const float* bnsc  = (const float*)d_in[10];
  const float* bnof  = (const float*)d_in[11];
  const float* ow    = (const float*)d_in[12];
  const float* ob    = (const float*)d_in[13];
  float* out = (float*)d_out;

  char* ws = (char*)d_ws;
  u16*   embT = (u16*)(ws + 0);
  u16*   z1b  = (u16*)(ws + 0);
  u16*   z2b  = (u16*)(ws + 100663296);
  u16*   gpb  = (u16*)(ws + 104857600);
  u16*   wlT  = (u16*)(ws + 146800640);
  u16*   pqqb = (u16*)(ws + 150077440);
  u16*   y0b  = (u16*)(ws + 151388160);
  u16*   w0T  = (u16*)(ws + 168165376);
  u16*   w1T  = (u16*)(ws + 169213952);
  float* S1a  = (float*)(ws + 170262528);
  float* S2a  = S1a + 1024;
  float* S1b  = S2a + 1024;
  float* S2b  = S1b + 512;
  float* cvec = S2b + 512;
  float* A0   = cvec + 1024;
  float* B0   = A0 + 1024;

  hipMemsetAsync((void*)S1a, 0, 16384, stream);      // S1a,S2a,S1b,S2b,cvec

  k_front<<<13344, 256, 0, stream>>>(fidx, fval, femb, embT, gpb,
                                     wl, wlT, pq, pqqb, w0, w0T, w1, w1T,
                                     pbias, b0, cvec);

  k_prod<<<512, 256, 0, stream>>>(embT, wlT, gpb, pqqb, pbias, y0b);

  // layer 0: z1c (centered bf16) + batch stats
  gemm_bt<<<2048, 256, 0, stream>>>(y0b, w0T, z1b, cvec, S1a, S2a,
                                    3, H1_SZ, D_SZ);
  k_bnfin<<<4, 256, 0, stream>>>(S1a, S2a, bnsc, bnof, cvec, A0, B0);

  // layer 1: BN(z1c)+relu fused into A-staging (T14 split); z2c + stats
  gemm_bn<<<1024, 256, 0, stream>>>(z1b, w1T, A0, B0, z2b, b1, S1b, S2b);

  k_out<<<4096, 256, 0, stream>>>(z2b, ow, ob, S1b, S2b, bnsc, bnof, b1, out);
}